// Round 13
// baseline (205.450 us; speedup 1.0000x reference)
//
#include <hip/hip_runtime.h>
#include <cstdint>
#include <cstddef>

#define L_SEQ 2048
#define BATCH 8
#define DIN   1024
#define PDIM  512
#define DOUT  1024
#define MROWS (L_SEQ * BATCH)   // 16384

typedef __attribute__((ext_vector_type(4))) float f32x4;
typedef __attribute__((ext_vector_type(8))) short bf16x8;

__device__ __forceinline__ unsigned short f2bf(float f) {
  union { float f; unsigned int u; } v; v.f = f;
  unsigned int u = v.u;
  unsigned int r = (u + 0x7FFFu + ((u >> 16) & 1u)) >> 16;
  return (unsigned short)r;
}
__device__ __forceinline__ float bf2f(unsigned short h) {
  union { unsigned int u; float f; } v; v.u = ((unsigned int)h) << 16;
  return v.f;
}

// async global->LDS, 16 bytes per lane; dest is wave-uniform base + lane*16
__device__ __forceinline__ void gld16(const unsigned short* g, unsigned short* l) {
  __builtin_amdgcn_global_load_lds(
      (const __attribute__((address_space(1))) void*)g,
      (__attribute__((address_space(3))) void*)l,
      16, 0, 0);
}

// T1: bijective XCD-chunked block remap (m204).
__device__ __forceinline__ int swz_lin(int lin, int nwg) {
  int q = nwg >> 3, r = nwg & 7;
  int xcd = lin & 7;
  int base = (xcd < r) ? xcd * (q + 1) : r * (q + 1) + (xcd - r) * q;
  return base + (lin >> 3);
}

// T2 LDS swizzle: logical 16B-chunk n of row r stored at position n ^ (r&7).
// Write side folds into the per-lane GLOBAL source column (gld16 dest linear);
// read side XORs the chunk index. Same involution both sides (rule #21).

// ---------------- fp32 -> bf16 convert (vectorized) ----------------
__global__ void convert_f32_bf16(const float* __restrict__ in,
                                 unsigned short* __restrict__ out, int n4) {
  int i = blockIdx.x * blockDim.x + threadIdx.x;
  int stride = gridDim.x * blockDim.x;
  for (; i < n4; i += stride) {
    float4 v = reinterpret_cast<const float4*>(in)[i];
    ushort4 o;
    o.x = f2bf(v.x); o.y = f2bf(v.y); o.z = f2bf(v.z); o.w = f2bf(v.w);
    reinterpret_cast<ushort4*>(out)[i] = o;
  }
}

// merged convert for the three weight tensors (one launch)
__global__ void convert3_f32_bf16(const float* __restrict__ a, unsigned short* __restrict__ oa, int na4,
                                  const float* __restrict__ b, unsigned short* __restrict__ ob, int nb4,
                                  const float* __restrict__ c, unsigned short* __restrict__ oc, int nc4) {
  int total = na4 + nb4 + nc4;
  for (int i = blockIdx.x * blockDim.x + threadIdx.x; i < total;
       i += gridDim.x * blockDim.x) {
    const float* in; unsigned short* out; int j = i;
    if (j < na4)            { in = a; out = oa; }
    else if (j < na4 + nb4) { j -= na4; in = b; out = ob; }
    else                    { j -= na4 + nb4; in = c; out = oc; }
    float4 v = reinterpret_cast<const float4*>(in)[j];
    ushort4 o;
    o.x = f2bf(v.x); o.y = f2bf(v.y); o.z = f2bf(v.z); o.w = f2bf(v.w);
    reinterpret_cast<ushort4*>(out)[j] = o;
  }
}

// ---------------- V transpose: kv[l][b][512+p] -> vt[b][p][l] ----------------
__global__ void transpose_v_kernel(const unsigned short* __restrict__ kv,
                                   unsigned short* __restrict__ vt) {
  __shared__ unsigned short tile[32][33];
  int b = blockIdx.z;
  int l0 = blockIdx.x * 32;
  int p0 = blockIdx.y * 32;
  const unsigned short* src = kv + (size_t)b * (2 * PDIM) + PDIM;
  unsigned short* dst = vt + (size_t)b * PDIM * L_SEQ;
  int tx = threadIdx.x, ty = threadIdx.y;
  #pragma unroll
  for (int r = ty; r < 32; r += 8)
    tile[r][tx] = src[(size_t)(l0 + r) * (BATCH * 2 * PDIM) + p0 + tx];
  __syncthreads();
  #pragma unroll
  for (int r = ty; r < 32; r += 8)
    dst[(size_t)(p0 + r) * L_SEQ + l0 + tx] = tile[tx][r];
}

// ---------------- row softmax, causal (bf16 in / in-place bf16 out), 512 thr -
__global__ void softmax_causal(unsigned short* __restrict__ S,
                               size_t strideB, float scale) {
  __shared__ float buf[L_SEQ];
  __shared__ float red[8];
  int b = blockIdx.z;
  int i = blockIdx.x;                       // causal row index
  unsigned short* row = S + b * strideB + (size_t)i * L_SEQ;
  int t = threadIdx.x;
  int lane = t & 63, wid = t >> 6;          // 8 waves

  float lmax = -3.0e38f;
  for (int j = t; j <= i; j += 512) {
    float v = bf2f(row[j]) * scale;
    buf[j] = v;
    lmax = fmaxf(lmax, v);
  }
  #pragma unroll
  for (int o = 32; o > 0; o >>= 1) lmax = fmaxf(lmax, __shfl_xor(lmax, o));
  if (lane == 0) red[wid] = lmax;
  __syncthreads();
  float m = fmaxf(fmaxf(fmaxf(red[0], red[1]), fmaxf(red[2], red[3])),
                  fmaxf(fmaxf(red[4], red[5]), fmaxf(red[6], red[7])));

  float lsum = 0.0f;
  for (int j = t; j <= i; j += 512) {
    float e = __expf(buf[j] - m);
    buf[j] = e;
    lsum += e;
  }
  #pragma unroll
  for (int o = 32; o > 0; o >>= 1) lsum += __shfl_xor(lsum, o);
  __syncthreads();
  if (lane == 0) red[wid] = lsum;
  __syncthreads();
  float inv = 1.0f / (red[0] + red[1] + red[2] + red[3] +
                      red[4] + red[5] + red[6] + red[7]);

  // PV's causal K-limit reads exactly up to the next 128-aligned boundary
  int jmax = ((i >> 7) + 1) << 7;
  for (int j = t; j < jmax; j += 512)
    row[j] = (j <= i) ? f2bf(buf[j] * inv) : (unsigned short)0;
}

// ---------------- bf16 MFMA GEMM: 2-phase dbuf + T1 + T2 -------------------
// EPI: 0 = store bf16, 1 = store fp32, 2 = store bf16 with residual add (R)
// mode: 0 = plain;
//       1 = causal lower-tri tile enumeration via bx (QK^T);
//       3 = plain grid with causal K-limit, row-tiles mapped DESCENDING in
//           work (tmTile = nt-1-by) so heavy blocks start first (PV).
#define BM 128
#define BK 64

template<int EPI, int TBN>
__global__ __launch_bounds__(256)
void gemm_bt(const unsigned short* __restrict__ A,
             const unsigned short* __restrict__ B,
             void* __restrict__ C,
             const unsigned short* __restrict__ R,
             int M, int N, int K, int lda, int ldb, int ldc,
             size_t sAb, size_t sBb, size_t sCb, size_t sRb,
             int mode) {
  constexpr int MF   = (TBN == 128) ? 4 : 2;
  constexpr int BITS = TBN / 32;

  int gx = gridDim.x, gy = gridDim.y;
  int nwg = gx * gy * (int)gridDim.z;
  int lin = ((int)blockIdx.z * gy + (int)blockIdx.y) * gx + (int)blockIdx.x;
  int wg = swz_lin(lin, nwg);
  int bx = wg % gx;
  int rem = wg / gx;
  int by = rem % gy;
  int bz = rem / gy;

  A += (size_t)bz * sAb;
  B += (size_t)bz * sBb;
  R += (size_t)bz * sRb;
  float* Cf = (float*)C + (size_t)bz * sCb;
  unsigned short* Ch = (unsigned short*)C + (size_t)bz * sCb;

  __shared__ unsigned short As[2][BM * BK];
  __shared__ unsigned short Bs[2][TBN * BK];

  int t = threadIdx.x;
  int lane = t & 63;
  int wid = t >> 6;
  int wr = (TBN == 128) ? (wid >> 1) * 64 : wid * 32;
  int wc = (TBN == 128) ? (wid & 1) * 64 : 0;
  int lr = lane & 15;
  int kof = (lane >> 4) * 8;
  int srow = lane >> 3;                       // staging row in 8-row group
  int scol = ((lane & 7) ^ srow) * 8;         // T2 pre-swizzled global col
  int rxor = (lane & 7) << 3;                 // T2 read-side XOR

  int tmTile, tnBase;
  if (mode == 1) {
    int t3 = bx;                              // linear lower-tri index
    int tm3 = 0;
    while ((tm3 + 1) * (tm3 + 2) / 2 <= t3) tm3++;
    tmTile = tm3;
    tnBase = (t3 - tm3 * (tm3 + 1) / 2) * TBN;
  } else if (mode == 3) {
    tmTile = (M / BM - 1) - by;               // descending work order
    tnBase = bx * TBN;
  } else {
    tmTile = by;
    tnBase = bx * TBN;
  }
  int tm = tmTile * BM;
  int kEnd = (mode == 3) ? ((tm + BM) < K ? (tm + BM) : K) : K;
  int nk = kEnd / BK;

  f32x4 acc[MF][4];
  f32x4 zero = {0.0f, 0.0f, 0.0f, 0.0f};
  #pragma unroll
  for (int m = 0; m < MF; ++m)
    #pragma unroll
    for (int n = 0; n < 4; ++n) acc[m][n] = zero;

  auto stage = [&](int bi, int ks) {
    int k0 = ks * BK;
    #pragma unroll
    for (int it = 0; it < 4; ++it) {
      int r = wid * 32 + it * 8;
      gld16(A + (size_t)(tm + r + srow) * lda + k0 + scol, &As[bi][r * BK]);
    }
    #pragma unroll
    for (int it = 0; it < BITS; ++it) {
      int r = wid * (TBN / 4) + it * 8;
      gld16(B + (size_t)(tnBase + r + srow) * ldb + k0 + scol, &Bs[bi][r * BK]);
    }
  };

  stage(0, 0);
  for (int ks = 0; ks < nk; ++ks) {
    int bi = ks & 1;
    if (ks + 1 < nk) {
      stage(bi ^ 1, ks + 1);
      if constexpr (TBN == 128)
        asm volatile("s_waitcnt vmcnt(8)" ::: "memory");
      else
        asm volatile("s_waitcnt vmcnt(6)" ::: "memory");
    } else {
      asm volatile("s_waitcnt vmcnt(0)" ::: "memory");
    }
    __builtin_amdgcn_s_barrier();
    __builtin_amdgcn_sched_barrier(0);

    #pragma unroll
    for (int kk = 0; kk < BK; kk += 32) {
      bf16x8 af[MF], bfr[4];
      #pragma unroll
      for (int m = 0; m < MF; ++m)
        af[m] = *(const bf16x8*)&As[bi][(wr + m * 16 + lr) * BK + ((kk + kof) ^ rxor)];
      #pragma unroll
      for (int n = 0; n < 4; ++n)
        bfr[n] = *(const bf16x8*)&Bs[bi][(wc + n * 16 + lr) * BK + ((kk + kof) ^ rxor)];
      #pragma unroll
      for (int m = 0; m < MF; ++m)
        #pragma unroll
        for (int n = 0; n < 4; ++n)
          acc[m][n] = __builtin_amdgcn_mfma_f32_16x16x32_bf16(af[m], bfr[n], acc[m][n], 0, 0, 0);
    }
    asm volatile("" ::: "memory");
    __builtin_amdgcn_s_barrier();
    __builtin_amdgcn_sched_barrier(0);
  }

  int rb0 = tm + wr + (lane >> 4) * 4;       // C/D: col=lane&15, row=(lane>>4)*4+j
  #pragma unroll
  for (int m = 0; m < MF; ++m) {
    #pragma unroll
    for (int n = 0; n < 4; ++n) {
      int col = tnBase + wc + n * 16 + lr;
      #pragma unroll
      for (int j = 0; j < 4; ++j) {
        int row = rb0 + m * 16 + j;
        float v = acc[m][n][j];
        size_t idx = (size_t)row * ldc + col;
        if constexpr (EPI == 1) {
          Cf[idx] = v;
        } else if constexpr (EPI == 2) {
          Ch[idx] = f2bf(v + bf2f(R[idx]));
        } else {
          Ch[idx] = f2bf(v);
        }
      }
    }
  }
}

// ---------------- fallback sentinel ----------------
__global__ void fill_kernel(float* out, int n, float v) {
  int i = blockIdx.x * blockDim.x + threadIdx.x;
  for (; i < n; i += gridDim.x * blockDim.x) out[i] = v;
}

extern "C" void kernel_launch(void* const* d_in, const int* in_sizes, int n_in,
                              void* d_out, int out_size, void* d_ws, size_t ws_size,
                              hipStream_t stream) {
  const float* x  = (const float*)d_in[0];
  const float* W1 = (const float*)d_in[1];
  const float* W2 = (const float*)d_in[2];
  const float* W3 = (const float*)d_in[3];
  float* out = (float*)d_out;

  char* ws = (char*)d_ws;
  size_t off = 0;
  auto alloc = [&](size_t bytes) -> char* {
    char* p = ws + off;
    off += (bytes + 255) & ~(size_t)255;
    return p;
  };

  unsigned short* zb  = (unsigned short*)alloc((size_t)MROWS * PDIM * 2);
  unsigned short* kvb = (unsigned short*)alloc((size_t)MROWS * 2 * PDIM * 2);
  unsigned short* vt  = (unsigned short*)alloc((size_t)BATCH * PDIM * L_SEQ * 2);
  unsigned short* ar  = (unsigned short*)alloc((size_t)MROWS * PDIM * 2);
  unsigned short* w3b = (unsigned short*)alloc((size_t)DOUT * PDIM * 2);
  size_t persist = off;

  char* scratch = ws + persist;
  size_t avail = (ws_size > persist) ? (ws_size - persist) : 0;

  size_t xbB  = ((size_t)MROWS * DIN * 2 + 255) & ~(size_t)255;
  size_t w1B  = ((size_t)PDIM * DIN * 2 + 255) & ~(size_t)255;
  size_t w2B  = ((size_t)2 * PDIM * PDIM * 2 + 255) & ~(size_t)255;
  size_t convNeed = xbB + w1B + w2B;

  size_t scores1 = ((size_t)L_SEQ * L_SEQ * 2 + 255) & ~(size_t)255; // 8MB bf16
  size_t per = scores1;

  if (avail < convNeed || avail < per) {
    float sentinel = 1.0e6f + (float)(ws_size >> 20);
    fill_kernel<<<512, 256, 0, stream>>>(out, out_size, sentinel);
    return;
  }

  int c = (int)(avail / per);
  if (c > BATCH) c = BATCH;
  int nch = (BATCH + c - 1) / c;
  c = (BATCH + nch - 1) / nch;

  unsigned short* xb  = (unsigned short*)(scratch);
  unsigned short* w1b = (unsigned short*)(scratch + xbB);
  unsigned short* w2b = (unsigned short*)(scratch + xbB + w1B);
  unsigned short* scores = (unsigned short*)(scratch);

  const float scaling = 0.04419417382415922f;  // 512^-0.5
  const int NTRI = (L_SEQ / BM) * (L_SEQ / BM + 1) / 2;   // 136 lower-tri tiles

  // converts: x alone (big), weights merged into one launch
  convert_f32_bf16<<<2048, 256, 0, stream>>>(x, xb, (MROWS * DIN) / 4);
  convert3_f32_bf16<<<768, 256, 0, stream>>>(
      W1, w1b, (PDIM * DIN) / 4,
      W2, w2b, (2 * PDIM * PDIM) / 4,
      W3, w3b, (DOUT * PDIM) / 4);

  // GEMM1: z = x @ W1^T   [16384,1024]x[512,1024] -> [16384,512] bf16
  gemm_bt<0, 128><<<dim3(PDIM / 128, MROWS / BM, 1), 256, 0, stream>>>(
      xb, w1b, zb, zb, MROWS, PDIM, DIN, DIN, DIN, PDIM, 0, 0, 0, 0, 0);

  // GEMM2: kv = z @ W2^T  [16384,512]x[1024,512] -> [16384,1024] bf16
  gemm_bt<0, 128><<<dim3(2 * PDIM / 128, MROWS / BM, 1), 256, 0, stream>>>(
      zb, w2b, kvb, zb, MROWS, 2 * PDIM, PDIM, PDIM, PDIM, 2 * PDIM, 0, 0, 0, 0, 0);

  // V transpose per batch: vt[b][p][l]
  transpose_v_kernel<<<dim3(L_SEQ / 32, PDIM / 32, BATCH), dim3(32, 8), 0, stream>>>(kvb, vt);

  // ---- chunked attention (c==8 expected: single pass) ----
  for (int b0 = 0; b0 < BATCH; b0 += c) {
    int cb = (BATCH - b0 < c) ? (BATCH - b0) : c;

    // scores[z] = Q @ K^T (bf16), triangular tile enumeration (mode 1)
    gemm_bt<0, 128><<<dim3(NTRI, 1, cb), 256, 0, stream>>>(
        zb + (size_t)b0 * PDIM, kvb + (size_t)b0 * 2 * PDIM, scores, zb,
        L_SEQ, L_SEQ, PDIM, BATCH * PDIM, BATCH * 2 * PDIM, L_SEQ,
        (size_t)PDIM, (size_t)2 * PDIM, (size_t)L_SEQ * L_SEQ, 0, 1);

    softmax_causal<<<dim3(L_SEQ, 1, cb), 512, 0, stream>>>(
        scores, (size_t)L_SEQ * L_SEQ, scaling);

    // attn_out + residual -> ar (bf16): unpaired causal row-tiles (mode 3)
    gemm_bt<2, 64><<<dim3(PDIM / 64, L_SEQ / BM, cb), 256, 0, stream>>>(
        scores, vt + (size_t)b0 * PDIM * L_SEQ, ar + (size_t)b0 * PDIM,
        zb + (size_t)b0 * PDIM,
        L_SEQ, PDIM, L_SEQ, L_SEQ, L_SEQ, BATCH * PDIM,
        (size_t)L_SEQ * L_SEQ, (size_t)PDIM * L_SEQ, (size_t)PDIM, (size_t)PDIM, 3);
  }

  // GEMM3: out = (attn + residual) @ W3^T -> fp32 d_out
  gemm_bt<1, 128><<<dim3(DOUT / 128, MROWS / BM, 1), 256, 0, stream>>>(
      ar, w3b, out, zb, MROWS, DOUT, PDIM, PDIM, PDIM, DOUT, 0, 0, 0, 0, 0);
}

// Round 14
// 185.532 us; speedup vs baseline: 1.1074x; 1.1074x over previous
//
#include <hip/hip_runtime.h>
#include <cstdint>
#include <cstddef>

#define L_SEQ 2048
#define BATCH 8
#define DIN   1024
#define PDIM  512
#define DOUT  1024
#define MROWS (L_SEQ * BATCH)   // 16384

typedef __attribute__((ext_vector_type(4))) float f32x4;
typedef __attribute__((ext_vector_type(8))) short bf16x8;

__device__ __forceinline__ unsigned short f2bf(float f) {
  union { float f; unsigned int u; } v; v.f = f;
  unsigned int u = v.u;
  unsigned int r = (u + 0x7FFFu + ((u >> 16) & 1u)) >> 16;
  return (unsigned short)r;
}
__device__ __forceinline__ float bf2f(unsigned short h) {
  union { unsigned int u; float f; } v; v.u = ((unsigned int)h) << 16;
  return v.f;
}

// async global->LDS, 16 bytes per lane; dest is wave-uniform base + lane*16
__device__ __forceinline__ void gld16(const unsigned short* g, unsigned short* l) {
  __builtin_amdgcn_global_load_lds(
      (const __attribute__((address_space(1))) void*)g,
      (__attribute__((address_space(3))) void*)l,
      16, 0, 0);
}

// T1: bijective XCD-chunked block remap (m204).
__device__ __forceinline__ int swz_lin(int lin, int nwg) {
  int q = nwg >> 3, r = nwg & 7;
  int xcd = lin & 7;
  int base = (xcd < r) ? xcd * (q + 1) : r * (q + 1) + (xcd - r) * q;
  return base + (lin >> 3);
}

// T2 LDS swizzle: logical 16B-chunk n of row r stored at position n ^ (r&7).
// Write side folds into the per-lane GLOBAL source column (gld16 dest linear);
// read side XORs the chunk index. Same involution both sides (rule #21).

// ---------------- fp32 -> bf16 convert (vectorized) ----------------
__global__ void convert_f32_bf16(const float* __restrict__ in,
                                 unsigned short* __restrict__ out, int n4) {
  int i = blockIdx.x * blockDim.x + threadIdx.x;
  int stride = gridDim.x * blockDim.x;
  for (; i < n4; i += stride) {
    float4 v = reinterpret_cast<const float4*>(in)[i];
    ushort4 o;
    o.x = f2bf(v.x); o.y = f2bf(v.y); o.z = f2bf(v.z); o.w = f2bf(v.w);
    reinterpret_cast<ushort4*>(out)[i] = o;
  }
}

// merged convert for the three weight tensors (one launch)
__global__ void convert3_f32_bf16(const float* __restrict__ a, unsigned short* __restrict__ oa, int na4,
                                  const float* __restrict__ b, unsigned short* __restrict__ ob, int nb4,
                                  const float* __restrict__ c, unsigned short* __restrict__ oc, int nc4) {
  int total = na4 + nb4 + nc4;
  for (int i = blockIdx.x * blockDim.x + threadIdx.x; i < total;
       i += gridDim.x * blockDim.x) {
    const float* in; unsigned short* out; int j = i;
    if (j < na4)            { in = a; out = oa; }
    else if (j < na4 + nb4) { j -= na4; in = b; out = ob; }
    else                    { j -= na4 + nb4; in = c; out = oc; }
    float4 v = reinterpret_cast<const float4*>(in)[j];
    ushort4 o;
    o.x = f2bf(v.x); o.y = f2bf(v.y); o.z = f2bf(v.z); o.w = f2bf(v.w);
    reinterpret_cast<ushort4*>(out)[j] = o;
  }
}

// ---------------- V transpose: kv[l][b][512+p] -> vt[b][p][l] ----------------
__global__ void transpose_v_kernel(const unsigned short* __restrict__ kv,
                                   unsigned short* __restrict__ vt) {
  __shared__ unsigned short tile[32][33];
  int b = blockIdx.z;
  int l0 = blockIdx.x * 32;
  int p0 = blockIdx.y * 32;
  const unsigned short* src = kv + (size_t)b * (2 * PDIM) + PDIM;
  unsigned short* dst = vt + (size_t)b * PDIM * L_SEQ;
  int tx = threadIdx.x, ty = threadIdx.y;
  #pragma unroll
  for (int r = ty; r < 32; r += 8)
    tile[r][tx] = src[(size_t)(l0 + r) * (BATCH * 2 * PDIM) + p0 + tx];
  __syncthreads();
  #pragma unroll
  for (int r = ty; r < 32; r += 8)
    dst[(size_t)(p0 + r) * L_SEQ + l0 + tx] = tile[tx][r];
}

// ---------------- row softmax, causal — vectorized register-resident -------
// 256 threads x 8 bf16 (16B/lane) = full 2048 row. One load pass, one store
// pass; masked lanes feed -3e38 -> exp()=0. Store skipped past the causal
// 128-aligned boundary (PV never reads there).
__global__ void softmax_causal(unsigned short* __restrict__ S,
                               size_t strideB, float scale) {
  __shared__ float red[4];
  int b = blockIdx.z;
  int i = blockIdx.x;                       // causal row index
  unsigned short* row = S + b * strideB + (size_t)i * L_SEQ;
  int t = threadIdx.x;                      // 0..255
  int lane = t & 63, wid = t >> 6;          // 4 waves
  int e0 = t * 8;

  bf16x8 h = *(const bf16x8*)&row[e0];
  float v[8];
  float lmax = -3.0e38f;
  #pragma unroll
  for (int k = 0; k < 8; ++k) {
    float f = bf2f((unsigned short)h[k]) * scale;
    v[k] = (e0 + k <= i) ? f : -3.0e38f;
    lmax = fmaxf(lmax, v[k]);
  }
  #pragma unroll
  for (int o = 32; o > 0; o >>= 1) lmax = fmaxf(lmax, __shfl_xor(lmax, o));
  if (lane == 0) red[wid] = lmax;
  __syncthreads();
  float m = fmaxf(fmaxf(red[0], red[1]), fmaxf(red[2], red[3]));
  __syncthreads();                          // red reuse

  float lsum = 0.0f;
  #pragma unroll
  for (int k = 0; k < 8; ++k) {
    v[k] = __expf(v[k] - m);                // invalid lanes -> 0
    lsum += v[k];
  }
  #pragma unroll
  for (int o = 32; o > 0; o >>= 1) lsum += __shfl_xor(lsum, o);
  if (lane == 0) red[wid] = lsum;
  __syncthreads();
  float inv = 1.0f / (red[0] + red[1] + red[2] + red[3]);

  int jmax = ((i >> 7) + 1) << 7;           // PV's causal K-limit boundary
  if (e0 < jmax) {
    bf16x8 o8;
    #pragma unroll
    for (int k = 0; k < 8; ++k)
      o8[k] = (short)((e0 + k <= i) ? f2bf(v[k] * inv) : (unsigned short)0);
    *(bf16x8*)&row[e0] = o8;
  }
}

// ---------------- bf16 MFMA GEMM: 2-phase dbuf + T1 + T2 -------------------
// EPI: 0 = store bf16, 1 = store fp32, 2 = store bf16 with residual add (R)
// mode: 0 = plain;
//       1 = causal lower-tri tile enumeration via bx (QK^T);
//       3 = plain grid with causal K-limit, row-tiles mapped DESCENDING in
//           work (tmTile = nt-1-by) so heavy blocks start first (PV).
#define BM 128
#define BK 64

template<int EPI, int TBN>
__global__ __launch_bounds__(256)
void gemm_bt(const unsigned short* __restrict__ A,
             const unsigned short* __restrict__ B,
             void* __restrict__ C,
             const unsigned short* __restrict__ R,
             int M, int N, int K, int lda, int ldb, int ldc,
             size_t sAb, size_t sBb, size_t sCb, size_t sRb,
             int mode) {
  constexpr int MF   = (TBN == 128) ? 4 : 2;
  constexpr int BITS = TBN / 32;

  int gx = gridDim.x, gy = gridDim.y;
  int nwg = gx * gy * (int)gridDim.z;
  int lin = ((int)blockIdx.z * gy + (int)blockIdx.y) * gx + (int)blockIdx.x;
  int wg = swz_lin(lin, nwg);
  int bx = wg % gx;
  int rem = wg / gx;
  int by = rem % gy;
  int bz = rem / gy;

  A += (size_t)bz * sAb;
  B += (size_t)bz * sBb;
  R += (size_t)bz * sRb;
  float* Cf = (float*)C + (size_t)bz * sCb;
  unsigned short* Ch = (unsigned short*)C + (size_t)bz * sCb;

  __shared__ unsigned short As[2][BM * BK];
  __shared__ unsigned short Bs[2][TBN * BK];

  int t = threadIdx.x;
  int lane = t & 63;
  int wid = t >> 6;
  int wr = (TBN == 128) ? (wid >> 1) * 64 : wid * 32;
  int wc = (TBN == 128) ? (wid & 1) * 64 : 0;
  int lr = lane & 15;
  int kof = (lane >> 4) * 8;
  int srow = lane >> 3;                       // staging row in 8-row group
  int scol = ((lane & 7) ^ srow) * 8;         // T2 pre-swizzled global col
  int rxor = (lane & 7) << 3;                 // T2 read-side XOR

  int tmTile, tnBase;
  if (mode == 1) {
    int t3 = bx;                              // linear lower-tri index
    int tm3 = 0;
    while ((tm3 + 1) * (tm3 + 2) / 2 <= t3) tm3++;
    tmTile = tm3;
    tnBase = (t3 - tm3 * (tm3 + 1) / 2) * TBN;
  } else if (mode == 3) {
    tmTile = (M / BM - 1) - by;               // descending work order
    tnBase = bx * TBN;
  } else {
    tmTile = by;
    tnBase = bx * TBN;
  }
  int tm = tmTile * BM;
  int kEnd = (mode == 3) ? ((tm + BM) < K ? (tm + BM) : K) : K;
  int nk = kEnd / BK;

  f32x4 acc[MF][4];
  f32x4 zero = {0.0f, 0.0f, 0.0f, 0.0f};
  #pragma unroll
  for (int m = 0; m < MF; ++m)
    #pragma unroll
    for (int n = 0; n < 4; ++n) acc[m][n] = zero;

  auto stage = [&](int bi, int ks) {
    int k0 = ks * BK;
    #pragma unroll
    for (int it = 0; it < 4; ++it) {
      int r = wid * 32 + it * 8;
      gld16(A + (size_t)(tm + r + srow) * lda + k0 + scol, &As[bi][r * BK]);
    }
    #pragma unroll
    for (int it = 0; it < BITS; ++it) {
      int r = wid * (TBN / 4) + it * 8;
      gld16(B + (size_t)(tnBase + r + srow) * ldb + k0 + scol, &Bs[bi][r * BK]);
    }
  };

  stage(0, 0);
  for (int ks = 0; ks < nk; ++ks) {
    int bi = ks & 1;
    if (ks + 1 < nk) {
      stage(bi ^ 1, ks + 1);
      if constexpr (TBN == 128)
        asm volatile("s_waitcnt vmcnt(8)" ::: "memory");
      else
        asm volatile("s_waitcnt vmcnt(6)" ::: "memory");
    } else {
      asm volatile("s_waitcnt vmcnt(0)" ::: "memory");
    }
    __builtin_amdgcn_s_barrier();
    __builtin_amdgcn_sched_barrier(0);

    #pragma unroll
    for (int kk = 0; kk < BK; kk += 32) {
      bf16x8 af[MF], bfr[4];
      #pragma unroll
      for (int m = 0; m < MF; ++m)
        af[m] = *(const bf16x8*)&As[bi][(wr + m * 16 + lr) * BK + ((kk + kof) ^ rxor)];
      #pragma unroll
      for (int n = 0; n < 4; ++n)
        bfr[n] = *(const bf16x8*)&Bs[bi][(wc + n * 16 + lr) * BK + ((kk + kof) ^ rxor)];
      #pragma unroll
      for (int m = 0; m < MF; ++m)
        #pragma unroll
        for (int n = 0; n < 4; ++n)
          acc[m][n] = __builtin_amdgcn_mfma_f32_16x16x32_bf16(af[m], bfr[n], acc[m][n], 0, 0, 0);
    }
    asm volatile("" ::: "memory");
    __builtin_amdgcn_s_barrier();
    __builtin_amdgcn_sched_barrier(0);
  }

  int rb0 = tm + wr + (lane >> 4) * 4;       // C/D: col=lane&15, row=(lane>>4)*4+j
  #pragma unroll
  for (int m = 0; m < MF; ++m) {
    #pragma unroll
    for (int n = 0; n < 4; ++n) {
      int col = tnBase + wc + n * 16 + lr;
      #pragma unroll
      for (int j = 0; j < 4; ++j) {
        int row = rb0 + m * 16 + j;
        float v = acc[m][n][j];
        size_t idx = (size_t)row * ldc + col;
        if constexpr (EPI == 1) {
          Cf[idx] = v;
        } else if constexpr (EPI == 2) {
          Ch[idx] = f2bf(v + bf2f(R[idx]));
        } else {
          Ch[idx] = f2bf(v);
        }
      }
    }
  }
}

// ---------------- fallback sentinel ----------------
__global__ void fill_kernel(float* out, int n, float v) {
  int i = blockIdx.x * blockDim.x + threadIdx.x;
  for (; i < n; i += gridDim.x * blockDim.x) out[i] = v;
}

extern "C" void kernel_launch(void* const* d_in, const int* in_sizes, int n_in,
                              void* d_out, int out_size, void* d_ws, size_t ws_size,
                              hipStream_t stream) {
  const float* x  = (const float*)d_in[0];
  const float* W1 = (const float*)d_in[1];
  const float* W2 = (const float*)d_in[2];
  const float* W3 = (const float*)d_in[3];
  float* out = (float*)d_out;

  char* ws = (char*)d_ws;
  size_t off = 0;
  auto alloc = [&](size_t bytes) -> char* {
    char* p = ws + off;
    off += (bytes + 255) & ~(size_t)255;
    return p;
  };

  unsigned short* zb  = (unsigned short*)alloc((size_t)MROWS * PDIM * 2);
  unsigned short* kvb = (unsigned short*)alloc((size_t)MROWS * 2 * PDIM * 2);
  unsigned short* vt  = (unsigned short*)alloc((size_t)BATCH * PDIM * L_SEQ * 2);
  unsigned short* ar  = (unsigned short*)alloc((size_t)MROWS * PDIM * 2);
  unsigned short* w3b = (unsigned short*)alloc((size_t)DOUT * PDIM * 2);
  size_t persist = off;

  char* scratch = ws + persist;
  size_t avail = (ws_size > persist) ? (ws_size - persist) : 0;

  size_t xbB  = ((size_t)MROWS * DIN * 2 + 255) & ~(size_t)255;
  size_t w1B  = ((size_t)PDIM * DIN * 2 + 255) & ~(size_t)255;
  size_t w2B  = ((size_t)2 * PDIM * PDIM * 2 + 255) & ~(size_t)255;
  size_t convNeed = xbB + w1B + w2B;

  size_t scores1 = ((size_t)L_SEQ * L_SEQ * 2 + 255) & ~(size_t)255; // 8MB bf16
  size_t per = scores1;

  if (avail < convNeed || avail < per) {
    float sentinel = 1.0e6f + (float)(ws_size >> 20);
    fill_kernel<<<512, 256, 0, stream>>>(out, out_size, sentinel);
    return;
  }

  int c = (int)(avail / per);
  if (c > BATCH) c = BATCH;
  int nch = (BATCH + c - 1) / c;
  c = (BATCH + nch - 1) / nch;

  unsigned short* xb  = (unsigned short*)(scratch);
  unsigned short* w1b = (unsigned short*)(scratch + xbB);
  unsigned short* w2b = (unsigned short*)(scratch + xbB + w1B);
  unsigned short* scores = (unsigned short*)(scratch);

  const float scaling = 0.04419417382415922f;  // 512^-0.5
  const int NTRI = (L_SEQ / BM) * (L_SEQ / BM + 1) / 2;   // 136 lower-tri tiles

  // converts: x alone (big), weights merged into one launch
  convert_f32_bf16<<<2048, 256, 0, stream>>>(x, xb, (MROWS * DIN) / 4);
  convert3_f32_bf16<<<768, 256, 0, stream>>>(
      W1, w1b, (PDIM * DIN) / 4,
      W2, w2b, (2 * PDIM * PDIM) / 4,
      W3, w3b, (DOUT * PDIM) / 4);

  // GEMM1: z = x @ W1^T   [16384,1024]x[512,1024] -> [16384,512] bf16
  gemm_bt<0, 128><<<dim3(PDIM / 128, MROWS / BM, 1), 256, 0, stream>>>(
      xb, w1b, zb, zb, MROWS, PDIM, DIN, DIN, DIN, PDIM, 0, 0, 0, 0, 0);

  // GEMM2: kv = z @ W2^T  [16384,512]x[1024,512] -> [16384,1024] bf16
  gemm_bt<0, 128><<<dim3(2 * PDIM / 128, MROWS / BM, 1), 256, 0, stream>>>(
      zb, w2b, kvb, zb, MROWS, 2 * PDIM, PDIM, PDIM, PDIM, 2 * PDIM, 0, 0, 0, 0, 0);

  // V transpose per batch: vt[b][p][l]
  transpose_v_kernel<<<dim3(L_SEQ / 32, PDIM / 32, BATCH), dim3(32, 8), 0, stream>>>(kvb, vt);

  // ---- chunked attention (c==8 expected: single pass) ----
  for (int b0 = 0; b0 < BATCH; b0 += c) {
    int cb = (BATCH - b0 < c) ? (BATCH - b0) : c;

    // scores[z] = Q @ K^T (bf16), triangular tile enumeration (mode 1)
    gemm_bt<0, 128><<<dim3(NTRI, 1, cb), 256, 0, stream>>>(
        zb + (size_t)b0 * PDIM, kvb + (size_t)b0 * 2 * PDIM, scores, zb,
        L_SEQ, L_SEQ, PDIM, BATCH * PDIM, BATCH * 2 * PDIM, L_SEQ,
        (size_t)PDIM, (size_t)2 * PDIM, (size_t)L_SEQ * L_SEQ, 0, 1);

    softmax_causal<<<dim3(L_SEQ, 1, cb), 256, 0, stream>>>(
        scores, (size_t)L_SEQ * L_SEQ, scaling);

    // attn_out + residual -> ar (bf16): unpaired causal row-tiles (mode 3)
    gemm_bt<2, 64><<<dim3(PDIM / 64, L_SEQ / BM, cb), 256, 0, stream>>>(
        scores, vt + (size_t)b0 * PDIM * L_SEQ, ar + (size_t)b0 * PDIM,
        zb + (size_t)b0 * PDIM,
        L_SEQ, PDIM, L_SEQ, L_SEQ, L_SEQ, BATCH * PDIM,
        (size_t)L_SEQ * L_SEQ, (size_t)PDIM * L_SEQ, (size_t)PDIM, (size_t)PDIM, 3);
  }

  // GEMM3: out = (attn + residual) @ W3^T -> fp32 d_out
  gemm_bt<1, 128><<<dim3(DOUT / 128, MROWS / BM, 1), 256, 0, stream>>>(
      ar, w3b, out, zb, MROWS, DOUT, PDIM, PDIM, PDIM, DOUT, 0, 0, 0, 0, 0);
}

// Round 15
// 185.237 us; speedup vs baseline: 1.1091x; 1.0016x over previous
//
#include <hip/hip_runtime.h>
#include <cstdint>
#include <cstddef>

#define L_SEQ 2048
#define BATCH 8
#define DIN   1024
#define PDIM  512
#define DOUT  1024
#define MROWS (L_SEQ * BATCH)   // 16384

typedef __attribute__((ext_vector_type(4))) float f32x4;
typedef __attribute__((ext_vector_type(8))) short bf16x8;

__device__ __forceinline__ unsigned short f2bf(float f) {
  union { float f; unsigned int u; } v; v.f = f;
  unsigned int u = v.u;
  unsigned int r = (u + 0x7FFFu + ((u >> 16) & 1u)) >> 16;
  return (unsigned short)r;
}
__device__ __forceinline__ float bf2f(unsigned short h) {
  union { unsigned int u; float f; } v; v.u = ((unsigned int)h) << 16;
  return v.f;
}

// async global->LDS, 16 bytes per lane; dest is wave-uniform base + lane*16
__device__ __forceinline__ void gld16(const unsigned short* g, unsigned short* l) {
  __builtin_amdgcn_global_load_lds(
      (const __attribute__((address_space(1))) void*)g,
      (__attribute__((address_space(3))) void*)l,
      16, 0, 0);
}

// T1: bijective XCD-chunked block remap (m204).
__device__ __forceinline__ int swz_lin(int lin, int nwg) {
  int q = nwg >> 3, r = nwg & 7;
  int xcd = lin & 7;
  int base = (xcd < r) ? xcd * (q + 1) : r * (q + 1) + (xcd - r) * q;
  return base + (lin >> 3);
}

// T2 LDS swizzle: logical 16B-chunk n of row r stored at position n ^ (r&7).
// gld16 path: swizzle folded into per-lane GLOBAL source col, linear LDS dest.
// reg-staged path (gemm_a32 A): identical content written via ds_write_b128.
// Read side XORs the chunk index. Same involution everywhere (rule #21).

// ---------------- fp32 -> bf16 convert (vectorized) ----------------
__global__ void convert_f32_bf16(const float* __restrict__ in,
                                 unsigned short* __restrict__ out, int n4) {
  int i = blockIdx.x * blockDim.x + threadIdx.x;
  int stride = gridDim.x * blockDim.x;
  for (; i < n4; i += stride) {
    float4 v = reinterpret_cast<const float4*>(in)[i];
    ushort4 o;
    o.x = f2bf(v.x); o.y = f2bf(v.y); o.z = f2bf(v.z); o.w = f2bf(v.w);
    reinterpret_cast<ushort4*>(out)[i] = o;
  }
}

// merged convert for the three weight tensors (one launch)
__global__ void convert3_f32_bf16(const float* __restrict__ a, unsigned short* __restrict__ oa, int na4,
                                  const float* __restrict__ b, unsigned short* __restrict__ ob, int nb4,
                                  const float* __restrict__ c, unsigned short* __restrict__ oc, int nc4) {
  int total = na4 + nb4 + nc4;
  for (int i = blockIdx.x * blockDim.x + threadIdx.x; i < total;
       i += gridDim.x * blockDim.x) {
    const float* in; unsigned short* out; int j = i;
    if (j < na4)            { in = a; out = oa; }
    else if (j < na4 + nb4) { j -= na4; in = b; out = ob; }
    else                    { j -= na4 + nb4; in = c; out = oc; }
    float4 v = reinterpret_cast<const float4*>(in)[j];
    ushort4 o;
    o.x = f2bf(v.x); o.y = f2bf(v.y); o.z = f2bf(v.z); o.w = f2bf(v.w);
    reinterpret_cast<ushort4*>(out)[j] = o;
  }
}

// ---------------- V transpose: kv[l][b][512+p] -> vt[b][p][l] ----------------
__global__ void transpose_v_kernel(const unsigned short* __restrict__ kv,
                                   unsigned short* __restrict__ vt) {
  __shared__ unsigned short tile[32][33];
  int b = blockIdx.z;
  int l0 = blockIdx.x * 32;
  int p0 = blockIdx.y * 32;
  const unsigned short* src = kv + (size_t)b * (2 * PDIM) + PDIM;
  unsigned short* dst = vt + (size_t)b * PDIM * L_SEQ;
  int tx = threadIdx.x, ty = threadIdx.y;
  #pragma unroll
  for (int r = ty; r < 32; r += 8)
    tile[r][tx] = src[(size_t)(l0 + r) * (BATCH * 2 * PDIM) + p0 + tx];
  __syncthreads();
  #pragma unroll
  for (int r = ty; r < 32; r += 8)
    dst[(size_t)(p0 + r) * L_SEQ + l0 + tx] = tile[tx][r];
}

// ---------------- row softmax, causal — vectorized register-resident -------
__global__ void softmax_causal(unsigned short* __restrict__ S,
                               size_t strideB, float scale) {
  __shared__ float red[4];
  int b = blockIdx.z;
  int i = blockIdx.x;                       // causal row index
  unsigned short* row = S + b * strideB + (size_t)i * L_SEQ;
  int t = threadIdx.x;                      // 0..255
  int lane = t & 63, wid = t >> 6;          // 4 waves
  int e0 = t * 8;

  bf16x8 h = *(const bf16x8*)&row[e0];
  float v[8];
  float lmax = -3.0e38f;
  #pragma unroll
  for (int k = 0; k < 8; ++k) {
    float f = bf2f((unsigned short)h[k]) * scale;
    v[k] = (e0 + k <= i) ? f : -3.0e38f;
    lmax = fmaxf(lmax, v[k]);
  }
  #pragma unroll
  for (int o = 32; o > 0; o >>= 1) lmax = fmaxf(lmax, __shfl_xor(lmax, o));
  if (lane == 0) red[wid] = lmax;
  __syncthreads();
  float m = fmaxf(fmaxf(red[0], red[1]), fmaxf(red[2], red[3]));
  __syncthreads();                          // red reuse

  float lsum = 0.0f;
  #pragma unroll
  for (int k = 0; k < 8; ++k) {
    v[k] = __expf(v[k] - m);                // invalid lanes -> 0
    lsum += v[k];
  }
  #pragma unroll
  for (int o = 32; o > 0; o >>= 1) lsum += __shfl_xor(lsum, o);
  if (lane == 0) red[wid] = lsum;
  __syncthreads();
  float inv = 1.0f / (red[0] + red[1] + red[2] + red[3]);

  int jmax = ((i >> 7) + 1) << 7;           // PV's causal K-limit boundary
  if (e0 < jmax) {
    bf16x8 o8;
    #pragma unroll
    for (int k = 0; k < 8; ++k)
      o8[k] = (short)((e0 + k <= i) ? f2bf(v[k] * inv) : (unsigned short)0);
    *(bf16x8*)&row[e0] = o8;
  }
}

// ---------------- bf16 MFMA GEMM: 2-phase dbuf + T1 + T2 -------------------
// EPI: 0 = store bf16, 1 = store fp32, 2 = store bf16 with residual add (R)
// mode: 0 = plain; 1 = causal lower-tri tiles (QK^T); 3 = causal K-limit,
//       rows descending in work (PV).
#define BM 128
#define BK 64

template<int EPI, int TBN>
__global__ __launch_bounds__(256)
void gemm_bt(const unsigned short* __restrict__ A,
             const unsigned short* __restrict__ B,
             void* __restrict__ C,
             const unsigned short* __restrict__ R,
             int M, int N, int K, int lda, int ldb, int ldc,
             size_t sAb, size_t sBb, size_t sCb, size_t sRb,
             int mode) {
  constexpr int MF   = (TBN == 128) ? 4 : 2;
  constexpr int BITS = TBN / 32;

  int gx = gridDim.x, gy = gridDim.y;
  int nwg = gx * gy * (int)gridDim.z;
  int lin = ((int)blockIdx.z * gy + (int)blockIdx.y) * gx + (int)blockIdx.x;
  int wg = swz_lin(lin, nwg);
  int bx = wg % gx;
  int rem = wg / gx;
  int by = rem % gy;
  int bz = rem / gy;

  A += (size_t)bz * sAb;
  B += (size_t)bz * sBb;
  R += (size_t)bz * sRb;
  float* Cf = (float*)C + (size_t)bz * sCb;
  unsigned short* Ch = (unsigned short*)C + (size_t)bz * sCb;

  __shared__ unsigned short As[2][BM * BK];
  __shared__ unsigned short Bs[2][TBN * BK];

  int t = threadIdx.x;
  int lane = t & 63;
  int wid = t >> 6;
  int wr = (TBN == 128) ? (wid >> 1) * 64 : wid * 32;
  int wc = (TBN == 128) ? (wid & 1) * 64 : 0;
  int lr = lane & 15;
  int kof = (lane >> 4) * 8;
  int srow = lane >> 3;                       // staging row in 8-row group
  int scol = ((lane & 7) ^ srow) * 8;         // T2 pre-swizzled global col
  int rxor = (lane & 7) << 3;                 // T2 read-side XOR

  int tmTile, tnBase;
  if (mode == 1) {
    int t3 = bx;                              // linear lower-tri index
    int tm3 = 0;
    while ((tm3 + 1) * (tm3 + 2) / 2 <= t3) tm3++;
    tmTile = tm3;
    tnBase = (t3 - tm3 * (tm3 + 1) / 2) * TBN;
  } else if (mode == 3) {
    tmTile = (M / BM - 1) - by;               // descending work order
    tnBase = bx * TBN;
  } else {
    tmTile = by;
    tnBase = bx * TBN;
  }
  int tm = tmTile * BM;
  int kEnd = (mode == 3) ? ((tm + BM) < K ? (tm + BM) : K) : K;
  int nk = kEnd / BK;

  f32x4 acc[MF][4];
  f32x4 zero = {0.0f, 0.0f, 0.0f, 0.0f};
  #pragma unroll
  for (int m = 0; m < MF; ++m)
    #pragma unroll
    for (int n = 0; n < 4; ++n) acc[m][n] = zero;

  auto stage = [&](int bi, int ks) {
    int k0 = ks * BK;
    #pragma unroll
    for (int it = 0; it < 4; ++it) {
      int r = wid * 32 + it * 8;
      gld16(A + (size_t)(tm + r + srow) * lda + k0 + scol, &As[bi][r * BK]);
    }
    #pragma unroll
    for (int it = 0; it < BITS; ++it) {
      int r = wid * (TBN / 4) + it * 8;
      gld16(B + (size_t)(tnBase + r + srow) * ldb + k0 + scol, &Bs[bi][r * BK]);
    }
  };

  stage(0, 0);
  for (int ks = 0; ks < nk; ++ks) {
    int bi = ks & 1;
    if (ks + 1 < nk) {
      stage(bi ^ 1, ks + 1);
      if constexpr (TBN == 128)
        asm volatile("s_waitcnt vmcnt(8)" ::: "memory");
      else
        asm volatile("s_waitcnt vmcnt(6)" ::: "memory");
    } else {
      asm volatile("s_waitcnt vmcnt(0)" ::: "memory");
    }
    __builtin_amdgcn_s_barrier();
    __builtin_amdgcn_sched_barrier(0);

    #pragma unroll
    for (int kk = 0; kk < BK; kk += 32) {
      bf16x8 af[MF], bfr[4];
      #pragma unroll
      for (int m = 0; m < MF; ++m)
        af[m] = *(const bf16x8*)&As[bi][(wr + m * 16 + lr) * BK + ((kk + kof) ^ rxor)];
      #pragma unroll
      for (int n = 0; n < 4; ++n)
        bfr[n] = *(const bf16x8*)&Bs[bi][(wc + n * 16 + lr) * BK + ((kk + kof) ^ rxor)];
      #pragma unroll
      for (int m = 0; m < MF; ++m)
        #pragma unroll
        for (int n = 0; n < 4; ++n)
          acc[m][n] = __builtin_amdgcn_mfma_f32_16x16x32_bf16(af[m], bfr[n], acc[m][n], 0, 0, 0);
    }
    asm volatile("" ::: "memory");
    __builtin_amdgcn_s_barrier();
    __builtin_amdgcn_sched_barrier(0);
  }

  int rb0 = tm + wr + (lane >> 4) * 4;       // C/D: col=lane&15, row=(lane>>4)*4+j
  #pragma unroll
  for (int m = 0; m < MF; ++m) {
    #pragma unroll
    for (int n = 0; n < 4; ++n) {
      int col = tnBase + wc + n * 16 + lr;
      #pragma unroll
      for (int j = 0; j < 4; ++j) {
        int row = rb0 + m * 16 + j;
        float v = acc[m][n][j];
        size_t idx = (size_t)row * ldc + col;
        if constexpr (EPI == 1) {
          Cf[idx] = v;
        } else if constexpr (EPI == 2) {
          Ch[idx] = f2bf(v + bf2f(R[idx]));
        } else {
          Ch[idx] = f2bf(v);
        }
      }
    }
  }
}

// ---------------- GEMM1 fused: fp32 A (reg-staged cvt) x bf16 B^T ----------
// A staged via regs: 2x float4/lane -> cvt -> ds_write_b128, producing the
// SAME swizzled LDS content as the gld16 path (LDS[row][chunk n] =
// global[row][8*(n^(row&7))]). ds_write placed post-compute so the fp32
// load latency hides under MFMA. B keeps the gld16 path. TBN=128, mode 0.
__global__ __launch_bounds__(256)
void gemm_a32(const float* __restrict__ A,
              const unsigned short* __restrict__ B,
              unsigned short* __restrict__ C,
              int M, int N, int K, int lda, int ldb, int ldc) {
  int gx = gridDim.x, gy = gridDim.y;
  int nwg = gx * gy;
  int lin = (int)blockIdx.y * gx + (int)blockIdx.x;
  int wg = swz_lin(lin, nwg);
  int bx = wg % gx;
  int by = wg / gx;

  __shared__ unsigned short As[2][BM * BK];
  __shared__ unsigned short Bs[2][BM * BK];   // TBN=128

  int t = threadIdx.x;
  int lane = t & 63;
  int wid = t >> 6;
  int wr = (wid >> 1) * 64;
  int wc = (wid & 1) * 64;
  int lr = lane & 15;
  int kof = (lane >> 4) * 8;
  int srow = lane >> 3;
  int scol = ((lane & 7) ^ srow) * 8;         // T2 pre-swizzled global col
  int rxor = (lane & 7) << 3;

  int tm = by * BM;
  int tnBase = bx * 128;
  int nk = K / BK;

  f32x4 acc[4][4];
  f32x4 zero = {0.0f, 0.0f, 0.0f, 0.0f};
  #pragma unroll
  for (int m = 0; m < 4; ++m)
    #pragma unroll
    for (int n = 0; n < 4; ++n) acc[m][n] = zero;

  float4 ar[4][2];                            // in-flight A tile (8 fp32/lane x 4 its)

  auto loadA = [&](int ks) {
    int k0 = ks * BK;
    #pragma unroll
    for (int it = 0; it < 4; ++it) {
      int r = wid * 32 + it * 8;
      const float4* p = reinterpret_cast<const float4*>(
          A + (size_t)(tm + r + srow) * lda + k0 + scol);
      ar[it][0] = p[0];
      ar[it][1] = p[1];
    }
  };
  auto writeA = [&](int bi) {
    #pragma unroll
    for (int it = 0; it < 4; ++it) {
      int r = wid * 32 + it * 8;
      bf16x8 h;
      h[0] = (short)f2bf(ar[it][0].x); h[1] = (short)f2bf(ar[it][0].y);
      h[2] = (short)f2bf(ar[it][0].z); h[3] = (short)f2bf(ar[it][0].w);
      h[4] = (short)f2bf(ar[it][1].x); h[5] = (short)f2bf(ar[it][1].y);
      h[6] = (short)f2bf(ar[it][1].z); h[7] = (short)f2bf(ar[it][1].w);
      *(bf16x8*)&As[bi][(r + srow) * BK + (lane & 7) * 8] = h;
    }
  };
  auto stageB = [&](int bi, int ks) {
    int k0 = ks * BK;
    #pragma unroll
    for (int it = 0; it < 4; ++it) {
      int r = wid * 32 + it * 8;
      gld16(B + (size_t)(tnBase + r + srow) * ldb + k0 + scol, &Bs[bi][r * BK]);
    }
  };

  // prologue: tile 0
  loadA(0);
  stageB(0, 0);
  writeA(0);                                  // compiler-inserted vmcnt for ar

  for (int ks = 0; ks < nk; ++ks) {
    int bi = ks & 1;
    if (ks + 1 < nk) {
      loadA(ks + 1);                          // 8 vm ops to regs
      stageB(bi ^ 1, ks + 1);                 // 4 vm ops to LDS
      asm volatile("s_waitcnt vmcnt(12)" ::: "memory");  // current B done
    } else {
      asm volatile("s_waitcnt vmcnt(0)" ::: "memory");
    }
    asm volatile("s_waitcnt lgkmcnt(0)" ::: "memory");   // my ds_writes drained
    __builtin_amdgcn_s_barrier();
    __builtin_amdgcn_sched_barrier(0);

    #pragma unroll
    for (int kk = 0; kk < BK; kk += 32) {
      bf16x8 af[4], bfr[4];
      #pragma unroll
      for (int m = 0; m < 4; ++m)
        af[m] = *(const bf16x8*)&As[bi][(wr + m * 16 + lr) * BK + ((kk + kof) ^ rxor)];
      #pragma unroll
      for (int n = 0; n < 4; ++n)
        bfr[n] = *(const bf16x8*)&Bs[bi][(wc + n * 16 + lr) * BK + ((kk + kof) ^ rxor)];
      #pragma unroll
      for (int m = 0; m < 4; ++m)
        #pragma unroll
        for (int n = 0; n < 4; ++n)
          acc[m][n] = __builtin_amdgcn_mfma_f32_16x16x32_bf16(af[m], bfr[n], acc[m][n], 0, 0, 0);
    }
    if (ks + 1 < nk) writeA(bi ^ 1);          // cvt+ds_write next A under MFMA tail
    asm volatile("" ::: "memory");
    __builtin_amdgcn_s_barrier();
    __builtin_amdgcn_sched_barrier(0);
  }

  int rb0 = tm + wr + (lane >> 4) * 4;
  #pragma unroll
  for (int m = 0; m < 4; ++m) {
    #pragma unroll
    for (int n = 0; n < 4; ++n) {
      int col = tnBase + wc + n * 16 + lr;
      #pragma unroll
      for (int j = 0; j < 4; ++j) {
        int row = rb0 + m * 16 + j;
        C[(size_t)row * ldc + col] = f2bf(acc[m][n][j]);
      }
    }
  }
}

// ---------------- fallback sentinel ----------------
__global__ void fill_kernel(float* out, int n, float v) {
  int i = blockIdx.x * blockDim.x + threadIdx.x;
  for (; i < n; i += gridDim.x * blockDim.x) out[i] = v;
}

extern "C" void kernel_launch(void* const* d_in, const int* in_sizes, int n_in,
                              void* d_out, int out_size, void* d_ws, size_t ws_size,
                              hipStream_t stream) {
  const float* x  = (const float*)d_in[0];
  const float* W1 = (const float*)d_in[1];
  const float* W2 = (const float*)d_in[2];
  const float* W3 = (const float*)d_in[3];
  float* out = (float*)d_out;

  char* ws = (char*)d_ws;
  size_t off = 0;
  auto alloc = [&](size_t bytes) -> char* {
    char* p = ws + off;
    off += (bytes + 255) & ~(size_t)255;
    return p;
  };

  unsigned short* zb  = (unsigned short*)alloc((size_t)MROWS * PDIM * 2);
  unsigned short* kvb = (unsigned short*)alloc((size_t)MROWS * 2 * PDIM * 2);
  unsigned short* vt  = (unsigned short*)alloc((size_t)BATCH * PDIM * L_SEQ * 2);
  unsigned short* ar  = (unsigned short*)alloc((size_t)MROWS * PDIM * 2);
  unsigned short* w3b = (unsigned short*)alloc((size_t)DOUT * PDIM * 2);
  size_t persist = off;

  char* scratch = ws + persist;
  size_t avail = (ws_size > persist) ? (ws_size - persist) : 0;

  size_t w1B  = ((size_t)PDIM * DIN * 2 + 255) & ~(size_t)255;
  size_t w2B  = ((size_t)2 * PDIM * PDIM * 2 + 255) & ~(size_t)255;
  size_t convNeed = w1B + w2B;

  size_t scores1 = ((size_t)L_SEQ * L_SEQ * 2 + 255) & ~(size_t)255; // 8MB bf16
  size_t per = scores1;

  if (avail < convNeed || avail < per) {
    float sentinel = 1.0e6f + (float)(ws_size >> 20);
    fill_kernel<<<512, 256, 0, stream>>>(out, out_size, sentinel);
    return;
  }

  int c = (int)(avail / per);
  if (c > BATCH) c = BATCH;
  int nch = (BATCH + c - 1) / c;
  c = (BATCH + nch - 1) / nch;

  unsigned short* w1b = (unsigned short*)(scratch);
  unsigned short* w2b = (unsigned short*)(scratch + w1B);
  unsigned short* scores = (unsigned short*)(scratch);  // overlaps w1b/w2b (consumed)

  const float scaling = 0.04419417382415922f;  // 512^-0.5
  const int NTRI = (L_SEQ / BM) * (L_SEQ / BM + 1) / 2;   // 136 lower-tri tiles

  // weights convert (one launch); x is consumed fp32 directly by gemm_a32
  convert3_f32_bf16<<<768, 256, 0, stream>>>(
      W1, w1b, (PDIM * DIN) / 4,
      W2, w2b, (2 * PDIM * PDIM) / 4,
      W3, w3b, (DOUT * PDIM) / 4);

  // GEMM1 (fused cvt): z = x @ W1^T  [16384,1024]fp32 x [512,1024] -> bf16
  gemm_a32<<<dim3(PDIM / 128, MROWS / BM, 1), 256, 0, stream>>>(
      x, w1b, zb, MROWS, PDIM, DIN, DIN, DIN, PDIM);

  // GEMM2: kv = z @ W2^T  [16384,512]x[1024,512] -> [16384,1024] bf16
  gemm_bt<0, 128><<<dim3(2 * PDIM / 128, MROWS / BM, 1), 256, 0, stream>>>(
      zb, w2b, kvb, zb, MROWS, 2 * PDIM, PDIM, PDIM, PDIM, 2 * PDIM, 0, 0, 0, 0, 0);

  // V transpose per batch: vt[b][p][l]
  transpose_v_kernel<<<dim3(L_SEQ / 32, PDIM / 32, BATCH), dim3(32, 8), 0, stream>>>(kvb, vt);

  // ---- chunked attention (c==8 expected: single pass) ----
  for (int b0 = 0; b0 < BATCH; b0 += c) {
    int cb = (BATCH - b0 < c) ? (BATCH - b0) : c;

    // scores[z] = Q @ K^T (bf16), triangular tile enumeration (mode 1)
    gemm_bt<0, 128><<<dim3(NTRI, 1, cb), 256, 0, stream>>>(
        zb + (size_t)b0 * PDIM, kvb + (size_t)b0 * 2 * PDIM, scores, zb,
        L_SEQ, L_SEQ, PDIM, BATCH * PDIM, BATCH * 2 * PDIM, L_SEQ,
        (size_t)PDIM, (size_t)2 * PDIM, (size_t)L_SEQ * L_SEQ, 0, 1);

    softmax_causal<<<dim3(L_SEQ, 1, cb), 256, 0, stream>>>(
        scores, (size_t)L_SEQ * L_SEQ, scaling);

    // attn_out + residual -> ar (bf16): unpaired causal row-tiles (mode 3)
    gemm_bt<2, 64><<<dim3(PDIM / 64, L_SEQ / BM, cb), 256, 0, stream>>>(
        scores, vt + (size_t)b0 * PDIM * L_SEQ, ar + (size_t)b0 * PDIM,
        zb + (size_t)b0 * PDIM,
        L_SEQ, PDIM, L_SEQ, L_SEQ, L_SEQ, BATCH * PDIM,
        (size_t)L_SEQ * L_SEQ, (size_t)PDIM * L_SEQ, (size_t)PDIM, (size_t)PDIM, 3);
  }

  // GEMM3: out = (attn + residual) @ W3^T -> fp32 d_out
  gemm_bt<1, 128><<<dim3(DOUT / 128, MROWS / BM, 1), 256, 0, stream>>>(
      ar, w3b, out, zb, MROWS, DOUT, PDIM, PDIM, PDIM, DOUT, 0, 0, 0, 0, 0);
}

// Round 16
// 178.540 us; speedup vs baseline: 1.1507x; 1.0375x over previous
//
#include <hip/hip_runtime.h>
#include <cstdint>
#include <cstddef>

#define L_SEQ 2048
#define BATCH 8
#define DIN   1024
#define PDIM  512
#define DOUT  1024
#define MROWS (L_SEQ * BATCH)   // 16384

typedef __attribute__((ext_vector_type(4))) float f32x4;
typedef __attribute__((ext_vector_type(8))) short bf16x8;

__device__ __forceinline__ unsigned short f2bf(float f) {
  union { float f; unsigned int u; } v; v.f = f;
  unsigned int u = v.u;
  unsigned int r = (u + 0x7FFFu + ((u >> 16) & 1u)) >> 16;
  return (unsigned short)r;
}
__device__ __forceinline__ float bf2f(unsigned short h) {
  union { unsigned int u; float f; } v; v.u = ((unsigned int)h) << 16;
  return v.f;
}

// async global->LDS, 16 bytes per lane; dest is wave-uniform base + lane*16
__device__ __forceinline__ void gld16(const unsigned short* g, unsigned short* l) {
  __builtin_amdgcn_global_load_lds(
      (const __attribute__((address_space(1))) void*)g,
      (__attribute__((address_space(3))) void*)l,
      16, 0, 0);
}

// T1: bijective XCD-chunked block remap (m204).
__device__ __forceinline__ int swz_lin(int lin, int nwg) {
  int q = nwg >> 3, r = nwg & 7;
  int xcd = lin & 7;
  int base = (xcd < r) ? xcd * (q + 1) : r * (q + 1) + (xcd - r) * q;
  return base + (lin >> 3);
}

// T2 LDS swizzle: logical 16B-chunk n of row r stored at position n ^ (r&7).
// gld16 path: swizzle folded into per-lane GLOBAL source col, linear LDS dest.
// Read side XORs the chunk index. Same involution everywhere (rule #21).

// ---------------- fp32 -> bf16 convert (vectorized) ----------------
__global__ void convert_f32_bf16(const float* __restrict__ in,
                                 unsigned short* __restrict__ out, int n4) {
  int i = blockIdx.x * blockDim.x + threadIdx.x;
  int stride = gridDim.x * blockDim.x;
  for (; i < n4; i += stride) {
    float4 v = reinterpret_cast<const float4*>(in)[i];
    ushort4 o;
    o.x = f2bf(v.x); o.y = f2bf(v.y); o.z = f2bf(v.z); o.w = f2bf(v.w);
    reinterpret_cast<ushort4*>(out)[i] = o;
  }
}

// merged convert for the three weight tensors (one launch)
__global__ void convert3_f32_bf16(const float* __restrict__ a, unsigned short* __restrict__ oa, int na4,
                                  const float* __restrict__ b, unsigned short* __restrict__ ob, int nb4,
                                  const float* __restrict__ c, unsigned short* __restrict__ oc, int nc4) {
  int total = na4 + nb4 + nc4;
  for (int i = blockIdx.x * blockDim.x + threadIdx.x; i < total;
       i += gridDim.x * blockDim.x) {
    const float* in; unsigned short* out; int j = i;
    if (j < na4)            { in = a; out = oa; }
    else if (j < na4 + nb4) { j -= na4; in = b; out = ob; }
    else                    { j -= na4 + nb4; in = c; out = oc; }
    float4 v = reinterpret_cast<const float4*>(in)[j];
    ushort4 o;
    o.x = f2bf(v.x); o.y = f2bf(v.y); o.z = f2bf(v.z); o.w = f2bf(v.w);
    reinterpret_cast<ushort4*>(out)[j] = o;
  }
}

// ---------------- V transpose: kv[l][b][512+p] -> vt[b][p][l] ----------------
__global__ void transpose_v_kernel(const unsigned short* __restrict__ kv,
                                   unsigned short* __restrict__ vt) {
  __shared__ unsigned short tile[32][33];
  int b = blockIdx.z;
  int l0 = blockIdx.x * 32;
  int p0 = blockIdx.y * 32;
  const unsigned short* src = kv + (size_t)b * (2 * PDIM) + PDIM;
  unsigned short* dst = vt + (size_t)b * PDIM * L_SEQ;
  int tx = threadIdx.x, ty = threadIdx.y;
  #pragma unroll
  for (int r = ty; r < 32; r += 8)
    tile[r][tx] = src[(size_t)(l0 + r) * (BATCH * 2 * PDIM) + p0 + tx];
  __syncthreads();
  #pragma unroll
  for (int r = ty; r < 32; r += 8)
    dst[(size_t)(p0 + r) * L_SEQ + l0 + tx] = tile[tx][r];
}

// ---------------- row softmax, causal — vectorized register-resident -------
__global__ void softmax_causal(unsigned short* __restrict__ S,
                               size_t strideB, float scale) {
  __shared__ float red[4];
  int b = blockIdx.z;
  int i = blockIdx.x;                       // causal row index
  unsigned short* row = S + b * strideB + (size_t)i * L_SEQ;
  int t = threadIdx.x;                      // 0..255
  int lane = t & 63, wid = t >> 6;          // 4 waves
  int e0 = t * 8;

  bf16x8 h = *(const bf16x8*)&row[e0];
  float v[8];
  float lmax = -3.0e38f;
  #pragma unroll
  for (int k = 0; k < 8; ++k) {
    float f = bf2f((unsigned short)h[k]) * scale;
    v[k] = (e0 + k <= i) ? f : -3.0e38f;
    lmax = fmaxf(lmax, v[k]);
  }
  #pragma unroll
  for (int o = 32; o > 0; o >>= 1) lmax = fmaxf(lmax, __shfl_xor(lmax, o));
  if (lane == 0) red[wid] = lmax;
  __syncthreads();
  float m = fmaxf(fmaxf(red[0], red[1]), fmaxf(red[2], red[3]));
  __syncthreads();                          // red reuse

  float lsum = 0.0f;
  #pragma unroll
  for (int k = 0; k < 8; ++k) {
    v[k] = __expf(v[k] - m);                // invalid lanes -> 0
    lsum += v[k];
  }
  #pragma unroll
  for (int o = 32; o > 0; o >>= 1) lsum += __shfl_xor(lsum, o);
  if (lane == 0) red[wid] = lsum;
  __syncthreads();
  float inv = 1.0f / (red[0] + red[1] + red[2] + red[3]);

  int jmax = ((i >> 7) + 1) << 7;           // PV's causal K-limit boundary
  if (e0 < jmax) {
    bf16x8 o8;
    #pragma unroll
    for (int k = 0; k < 8; ++k)
      o8[k] = (short)((e0 + k <= i) ? f2bf(v[k] * inv) : (unsigned short)0);
    *(bf16x8*)&row[e0] = o8;
  }
}

// ---------------- bf16 MFMA GEMM (256 thr): 2-phase dbuf + T1 + T2 ---------
// Used for PV (TBN=64, mode 3, EPI 2).
// EPI: 0 bf16, 1 fp32, 2 bf16 + residual add. mode: 0 plain; 1 tri; 3 causal
// K-limit rows-descending.
#define BM 128
#define BK 64

template<int EPI, int TBN>
__global__ __launch_bounds__(256)
void gemm_bt(const unsigned short* __restrict__ A,
             const unsigned short* __restrict__ B,
             void* __restrict__ C,
             const unsigned short* __restrict__ R,
             int M, int N, int K, int lda, int ldb, int ldc,
             size_t sAb, size_t sBb, size_t sCb, size_t sRb,
             int mode) {
  constexpr int MF   = (TBN == 128) ? 4 : 2;
  constexpr int BITS = TBN / 32;

  int gx = gridDim.x, gy = gridDim.y;
  int nwg = gx * gy * (int)gridDim.z;
  int lin = ((int)blockIdx.z * gy + (int)blockIdx.y) * gx + (int)blockIdx.x;
  int wg = swz_lin(lin, nwg);
  int bx = wg % gx;
  int rem = wg / gx;
  int by = rem % gy;
  int bz = rem / gy;

  A += (size_t)bz * sAb;
  B += (size_t)bz * sBb;
  R += (size_t)bz * sRb;
  float* Cf = (float*)C + (size_t)bz * sCb;
  unsigned short* Ch = (unsigned short*)C + (size_t)bz * sCb;

  __shared__ unsigned short As[2][BM * BK];
  __shared__ unsigned short Bs[2][TBN * BK];

  int t = threadIdx.x;
  int lane = t & 63;
  int wid = t >> 6;
  int wr = (TBN == 128) ? (wid >> 1) * 64 : wid * 32;
  int wc = (TBN == 128) ? (wid & 1) * 64 : 0;
  int lr = lane & 15;
  int kof = (lane >> 4) * 8;
  int srow = lane >> 3;
  int scol = ((lane & 7) ^ srow) * 8;         // T2 pre-swizzled global col
  int rxor = (lane & 7) << 3;                 // T2 read-side XOR

  int tmTile, tnBase;
  if (mode == 1) {
    int t3 = bx;
    int tm3 = 0;
    while ((tm3 + 1) * (tm3 + 2) / 2 <= t3) tm3++;
    tmTile = tm3;
    tnBase = (t3 - tm3 * (tm3 + 1) / 2) * TBN;
  } else if (mode == 3) {
    tmTile = (M / BM - 1) - by;               // descending work order
    tnBase = bx * TBN;
  } else {
    tmTile = by;
    tnBase = bx * TBN;
  }
  int tm = tmTile * BM;
  int kEnd = (mode == 3) ? ((tm + BM) < K ? (tm + BM) : K) : K;
  int nk = kEnd / BK;

  f32x4 acc[MF][4];
  f32x4 zero = {0.0f, 0.0f, 0.0f, 0.0f};
  #pragma unroll
  for (int m = 0; m < MF; ++m)
    #pragma unroll
    for (int n = 0; n < 4; ++n) acc[m][n] = zero;

  auto stage = [&](int bi, int ks) {
    int k0 = ks * BK;
    #pragma unroll
    for (int it = 0; it < 4; ++it) {
      int r = wid * 32 + it * 8;
      gld16(A + (size_t)(tm + r + srow) * lda + k0 + scol, &As[bi][r * BK]);
    }
    #pragma unroll
    for (int it = 0; it < BITS; ++it) {
      int r = wid * (TBN / 4) + it * 8;
      gld16(B + (size_t)(tnBase + r + srow) * ldb + k0 + scol, &Bs[bi][r * BK]);
    }
  };

  stage(0, 0);
  for (int ks = 0; ks < nk; ++ks) {
    int bi = ks & 1;
    if (ks + 1 < nk) {
      stage(bi ^ 1, ks + 1);
      if constexpr (TBN == 128)
        asm volatile("s_waitcnt vmcnt(8)" ::: "memory");
      else
        asm volatile("s_waitcnt vmcnt(6)" ::: "memory");
    } else {
      asm volatile("s_waitcnt vmcnt(0)" ::: "memory");
    }
    __builtin_amdgcn_s_barrier();
    __builtin_amdgcn_sched_barrier(0);

    #pragma unroll
    for (int kk = 0; kk < BK; kk += 32) {
      bf16x8 af[MF], bfr[4];
      #pragma unroll
      for (int m = 0; m < MF; ++m)
        af[m] = *(const bf16x8*)&As[bi][(wr + m * 16 + lr) * BK + ((kk + kof) ^ rxor)];
      #pragma unroll
      for (int n = 0; n < 4; ++n)
        bfr[n] = *(const bf16x8*)&Bs[bi][(wc + n * 16 + lr) * BK + ((kk + kof) ^ rxor)];
      #pragma unroll
      for (int m = 0; m < MF; ++m)
        #pragma unroll
        for (int n = 0; n < 4; ++n)
          acc[m][n] = __builtin_amdgcn_mfma_f32_16x16x32_bf16(af[m], bfr[n], acc[m][n], 0, 0, 0);
    }
    asm volatile("" ::: "memory");
    __builtin_amdgcn_s_barrier();
    __builtin_amdgcn_sched_barrier(0);
  }

  int rb0 = tm + wr + (lane >> 4) * 4;
  #pragma unroll
  for (int m = 0; m < MF; ++m) {
    #pragma unroll
    for (int n = 0; n < 4; ++n) {
      int col = tnBase + wc + n * 16 + lr;
      #pragma unroll
      for (int j = 0; j < 4; ++j) {
        int row = rb0 + m * 16 + j;
        float v = acc[m][n][j];
        size_t idx = (size_t)row * ldc + col;
        if constexpr (EPI == 1) {
          Cf[idx] = v;
        } else if constexpr (EPI == 2) {
          Ch[idx] = f2bf(v + bf2f(R[idx]));
        } else {
          Ch[idx] = f2bf(v);
        }
      }
    }
  }
}

// ---------------- bf16 MFMA GEMM (512 thr / 8 waves): 128² tile ------------
// Same 2-phase dbuf + T1 + T2, same 64KB LDS -> 2 blocks/CU but 16 waves/CU
// (4/SIMD) for doubled latency cover. Wave (wm,wn) owns a 32x64 sub-tile.
// EPI: 0 bf16, 1 fp32. MODE: 0 plain, 1 causal lower-tri enumeration.
template<int EPI, int MODE>
__global__ __launch_bounds__(512)
void gemm_bt8(const unsigned short* __restrict__ A,
              const unsigned short* __restrict__ B,
              void* __restrict__ C,
              int K, int lda, int ldb, int ldc,
              size_t sAb, size_t sBb, size_t sCb) {
  int gx = gridDim.x, gy = gridDim.y;
  int nwg = gx * gy * (int)gridDim.z;
  int lin = ((int)blockIdx.z * gy + (int)blockIdx.y) * gx + (int)blockIdx.x;
  int wg = swz_lin(lin, nwg);
  int bx = wg % gx;
  int rem = wg / gx;
  int by = rem % gy;
  int bz = rem / gy;

  A += (size_t)bz * sAb;
  B += (size_t)bz * sBb;
  float* Cf = (float*)C + (size_t)bz * sCb;
  unsigned short* Ch = (unsigned short*)C + (size_t)bz * sCb;

  __shared__ unsigned short As[2][BM * BK];
  __shared__ unsigned short Bs[2][BM * BK];   // 128x64

  int t = threadIdx.x;
  int lane = t & 63;
  int wid = t >> 6;                           // 0..7
  int wm = wid >> 1;                          // 0..3 -> rows wm*32
  int wn = wid & 1;                           // 0..1 -> cols wn*64
  int lr = lane & 15;
  int kof = (lane >> 4) * 8;
  int srow = lane >> 3;
  int scol = ((lane & 7) ^ srow) * 8;         // T2 pre-swizzled global col
  int rxor = (lane & 7) << 3;                 // T2 read-side XOR

  int tmTile, tnBase;
  if (MODE == 1) {
    int t3 = bx;
    int tm3 = 0;
    while ((tm3 + 1) * (tm3 + 2) / 2 <= t3) tm3++;
    tmTile = tm3;
    tnBase = (t3 - tm3 * (tm3 + 1) / 2) * 128;
  } else {
    tmTile = by;
    tnBase = bx * 128;
  }
  int tm = tmTile * BM;
  int nk = K / BK;

  f32x4 acc[2][4];
  f32x4 zero = {0.0f, 0.0f, 0.0f, 0.0f};
  #pragma unroll
  for (int m = 0; m < 2; ++m)
    #pragma unroll
    for (int n = 0; n < 4; ++n) acc[m][n] = zero;

  // stage: 512 threads, 2 calls/operand (wave wid covers rows it*64+wid*8..+8)
  auto stage = [&](int bi, int ks) {
    int k0 = ks * BK;
    #pragma unroll
    for (int it = 0; it < 2; ++it) {
      int r = it * 64 + wid * 8;
      gld16(A + (size_t)(tm + r + srow) * lda + k0 + scol, &As[bi][r * BK]);
    }
    #pragma unroll
    for (int it = 0; it < 2; ++it) {
      int r = it * 64 + wid * 8;
      gld16(B + (size_t)(tnBase + r + srow) * ldb + k0 + scol, &Bs[bi][r * BK]);
    }
  };

  stage(0, 0);
  for (int ks = 0; ks < nk; ++ks) {
    int bi = ks & 1;
    if (ks + 1 < nk) {
      stage(bi ^ 1, ks + 1);
      asm volatile("s_waitcnt vmcnt(4)" ::: "memory");  // current tile's 4 done
    } else {
      asm volatile("s_waitcnt vmcnt(0)" ::: "memory");
    }
    __builtin_amdgcn_s_barrier();
    __builtin_amdgcn_sched_barrier(0);

    #pragma unroll
    for (int kk = 0; kk < BK; kk += 32) {
      bf16x8 af[2], bfr[4];
      #pragma unroll
      for (int m = 0; m < 2; ++m)
        af[m] = *(const bf16x8*)&As[bi][(wm * 32 + m * 16 + lr) * BK + ((kk + kof) ^ rxor)];
      #pragma unroll
      for (int n = 0; n < 4; ++n)
        bfr[n] = *(const bf16x8*)&Bs[bi][(wn * 64 + n * 16 + lr) * BK + ((kk + kof) ^ rxor)];
      #pragma unroll
      for (int m = 0; m < 2; ++m)
        #pragma unroll
        for (int n = 0; n < 4; ++n)
          acc[m][n] = __builtin_amdgcn_mfma_f32_16x16x32_bf16(af[m], bfr[n], acc[m][n], 0, 0, 0);
    }
    asm volatile("" ::: "memory");
    __builtin_amdgcn_s_barrier();
    __builtin_amdgcn_sched_barrier(0);
  }

  int rb0 = tm + wm * 32 + (lane >> 4) * 4;   // C/D: col=lane&15, row=(lane>>4)*4+j
  #pragma unroll
  for (int m = 0; m < 2; ++m) {
    #pragma unroll
    for (int n = 0; n < 4; ++n) {
      int col = tnBase + wn * 64 + n * 16 + lr;
      #pragma unroll
      for (int j = 0; j < 4; ++j) {
        int row = rb0 + m * 16 + j;
        float v = acc[m][n][j];
        size_t idx = (size_t)row * ldc + col;
        if constexpr (EPI == 1) Cf[idx] = v;
        else                    Ch[idx] = f2bf(v);
      }
    }
  }
}

// ---------------- GEMM1 fused: fp32 A (reg-staged cvt) x bf16 B^T ----------
__global__ __launch_bounds__(256)
void gemm_a32(const float* __restrict__ A,
              const unsigned short* __restrict__ B,
              unsigned short* __restrict__ C,
              int M, int N, int K, int lda, int ldb, int ldc) {
  int gx = gridDim.x, gy = gridDim.y;
  int nwg = gx * gy;
  int lin = (int)blockIdx.y * gx + (int)blockIdx.x;
  int wg = swz_lin(lin, nwg);
  int bx = wg % gx;
  int by = wg / gx;

  __shared__ unsigned short As[2][BM * BK];
  __shared__ unsigned short Bs[2][BM * BK];   // TBN=128

  int t = threadIdx.x;
  int lane = t & 63;
  int wid = t >> 6;
  int wr = (wid >> 1) * 64;
  int wc = (wid & 1) * 64;
  int lr = lane & 15;
  int kof = (lane >> 4) * 8;
  int srow = lane >> 3;
  int scol = ((lane & 7) ^ srow) * 8;         // T2 pre-swizzled global col
  int rxor = (lane & 7) << 3;

  int tm = by * BM;
  int tnBase = bx * 128;
  int nk = K / BK;

  f32x4 acc[4][4];
  f32x4 zero = {0.0f, 0.0f, 0.0f, 0.0f};
  #pragma unroll
  for (int m = 0; m < 4; ++m)
    #pragma unroll
    for (int n = 0; n < 4; ++n) acc[m][n] = zero;

  float4 ar[4][2];                            // in-flight A tile

  auto loadA = [&](int ks) {
    int k0 = ks * BK;
    #pragma unroll
    for (int it = 0; it < 4; ++it) {
      int r = wid * 32 + it * 8;
      const float4* p = reinterpret_cast<const float4*>(
          A + (size_t)(tm + r + srow) * lda + k0 + scol);
      ar[it][0] = p[0];
      ar[it][1] = p[1];
    }
  };
  auto writeA = [&](int bi) {
    #pragma unroll
    for (int it = 0; it < 4; ++it) {
      int r = wid * 32 + it * 8;
      bf16x8 h;
      h[0] = (short)f2bf(ar[it][0].x); h[1] = (short)f2bf(ar[it][0].y);
      h[2] = (short)f2bf(ar[it][0].z); h[3] = (short)f2bf(ar[it][0].w);
      h[4] = (short)f2bf(ar[it][1].x); h[5] = (short)f2bf(ar[it][1].y);
      h[6] = (short)f2bf(ar[it][1].z); h[7] = (short)f2bf(ar[it][1].w);
      *(bf16x8*)&As[bi][(r + srow) * BK + (lane & 7) * 8] = h;
    }
  };
  auto stageB = [&](int bi, int ks) {
    int k0 = ks * BK;
    #pragma unroll
    for (int it = 0; it < 4; ++it) {
      int r = wid * 32 + it * 8;
      gld16(B + (size_t)(tnBase + r + srow) * ldb + k0 + scol, &Bs[bi][r * BK]);
    }
  };

  loadA(0);
  stageB(0, 0);
  writeA(0);

  for (int ks = 0; ks < nk; ++ks) {
    int bi = ks & 1;
    if (ks + 1 < nk) {
      loadA(ks + 1);
      stageB(bi ^ 1, ks + 1);
      asm volatile("s_waitcnt vmcnt(12)" ::: "memory");
    } else {
      asm volatile("s_waitcnt vmcnt(0)" ::: "memory");
    }
    asm volatile("s_waitcnt lgkmcnt(0)" ::: "memory");
    __builtin_amdgcn_s_barrier();
    __builtin_amdgcn_sched_barrier(0);

    #pragma unroll
    for (int kk = 0; kk < BK; kk += 32) {
      bf16x8 af[4], bfr[4];
      #pragma unroll
      for (int m = 0; m < 4; ++m)
        af[m] = *(const bf16x8*)&As[bi][(wr + m * 16 + lr) * BK + ((kk + kof) ^ rxor)];
      #pragma unroll
      for (int n = 0; n < 4; ++n)
        bfr[n] = *(const bf16x8*)&Bs[bi][(wc + n * 16 + lr) * BK + ((kk + kof) ^ rxor)];
      #pragma unroll
      for (int m = 0; m < 4; ++m)
        #pragma unroll
        for (int n = 0; n < 4; ++n)
          acc[m][n] = __builtin_amdgcn_mfma_f32_16x16x32_bf16(af[m], bfr[n], acc[m][n], 0, 0, 0);
    }
    if (ks + 1 < nk) writeA(bi ^ 1);
    asm volatile("" ::: "memory");
    __builtin_amdgcn_s_barrier();
    __builtin_amdgcn_sched_barrier(0);
  }

  int rb0 = tm + wr + (lane >> 4) * 4;
  #pragma unroll
  for (int m = 0; m < 4; ++m) {
    #pragma unroll
    for (int n = 0; n < 4; ++n) {
      int col = tnBase + wc + n * 16 + lr;
      #pragma unroll
      for (int j = 0; j < 4; ++j) {
        int row = rb0 + m * 16 + j;
        C[(size_t)row * ldc + col] = f2bf(acc[m][n][j]);
      }
    }
  }
}

// ---------------- fallback sentinel ----------------
__global__ void fill_kernel(float* out, int n, float v) {
  int i = blockIdx.x * blockDim.x + threadIdx.x;
  for (; i < n; i += gridDim.x * blockDim.x) out[i] = v;
}

extern "C" void kernel_launch(void* const* d_in, const int* in_sizes, int n_in,
                              void* d_out, int out_size, void* d_ws, size_t ws_size,
                              hipStream_t stream) {
  const float* x  = (const float*)d_in[0];
  const float* W1 = (const float*)d_in[1];
  const float* W2 = (const float*)d_in[2];
  const float* W3 = (const float*)d_in[3];
  float* out = (float*)d_out;

  char* ws = (char*)d_ws;
  size_t off = 0;
  auto alloc = [&](size_t bytes) -> char* {
    char* p = ws + off;
    off += (bytes + 255) & ~(size_t)255;
    return p;
  };

  unsigned short* zb  = (unsigned short*)alloc((size_t)MROWS * PDIM * 2);
  unsigned short* kvb = (unsigned short*)alloc((size_t)MROWS * 2 * PDIM * 2);
  unsigned short* vt  = (unsigned short*)alloc((size_t)BATCH * PDIM * L_SEQ * 2);
  unsigned short* ar  = (unsigned short*)alloc((size_t)MROWS * PDIM * 2);
  unsigned short* w3b = (unsigned short*)alloc((size_t)DOUT * PDIM * 2);
  size_t persist = off;

  char* scratch = ws + persist;
  size_t avail = (ws_size > persist) ? (ws_size - persist) : 0;

  size_t w1B  = ((size_t)PDIM * DIN * 2 + 255) & ~(size_t)255;
  size_t w2B  = ((size_t)2 * PDIM * PDIM * 2 + 255) & ~(size_t)255;
  size_t convNeed = w1B + w2B;

  size_t scores1 = ((size_t)L_SEQ * L_SEQ * 2 + 255) & ~(size_t)255; // 8MB bf16
  size_t per = scores1;

  if (avail < convNeed || avail < per) {
    float sentinel = 1.0e6f + (float)(ws_size >> 20);
    fill_kernel<<<512, 256, 0, stream>>>(out, out_size, sentinel);
    return;
  }

  int c = (int)(avail / per);
  if (c > BATCH) c = BATCH;
  int nch = (BATCH + c - 1) / c;
  c = (BATCH + nch - 1) / nch;

  unsigned short* w1b = (unsigned short*)(scratch);
  unsigned short* w2b = (unsigned short*)(scratch + w1B);
  unsigned short* scores = (unsigned short*)(scratch);  // overlaps w1b/w2b (consumed)

  const float scaling = 0.04419417382415922f;  // 512^-0.5
  const int NTRI = (L_SEQ / BM) * (L_SEQ / BM + 1) / 2;   // 136 lower-tri tiles

  // weights convert (one launch); x is consumed fp32 directly by gemm_a32
  convert3_f32_bf16<<<768, 256, 0, stream>>>(
      W1, w1b, (PDIM * DIN) / 4,
      W2, w2b, (2 * PDIM * PDIM) / 4,
      W3, w3b, (DOUT * PDIM) / 4);

  // GEMM1 (fused cvt): z = x @ W1^T  [16384,1024]fp32 x [512,1024] -> bf16
  gemm_a32<<<dim3(PDIM / 128, MROWS / BM, 1), 256, 0, stream>>>(
      x, w1b, zb, MROWS, PDIM, DIN, DIN, DIN, PDIM);

  // GEMM2: kv = z @ W2^T -> 8-wave 512-thread kernel
  gemm_bt8<0, 0><<<dim3(2 * PDIM / 128, MROWS / BM, 1), 512, 0, stream>>>(
      zb, w2b, kvb, PDIM, PDIM, PDIM, 2 * PDIM, 0, 0, 0);

  // V transpose per batch: vt[b][p][l]
  transpose_v_kernel<<<dim3(L_SEQ / 32, PDIM / 32, BATCH), dim3(32, 8), 0, stream>>>(kvb, vt);

  // ---- chunked attention (c==8 expected: single pass) ----
  for (int b0 = 0; b0 < BATCH; b0 += c) {
    int cb = (BATCH - b0 < c) ? (BATCH - b0) : c;

    // scores[z] = Q @ K^T (bf16), triangular tiles, 8-wave kernel
    gemm_bt8<0, 1><<<dim3(NTRI, 1, cb), 512, 0, stream>>>(
        zb + (size_t)b0 * PDIM, kvb + (size_t)b0 * 2 * PDIM, scores,
        PDIM, BATCH * PDIM, BATCH * 2 * PDIM, L_SEQ,
        (size_t)PDIM, (size_t)2 * PDIM, (size_t)L_SEQ * L_SEQ);

    softmax_causal<<<dim3(L_SEQ, 1, cb), 256, 0, stream>>>(
        scores, (size_t)L_SEQ * L_SEQ, scaling);

    // attn_out + residual -> ar (bf16): unpaired causal row-tiles (mode 3)
    gemm_bt<2, 64><<<dim3(PDIM / 64, L_SEQ / BM, cb), 256, 0, stream>>>(
        scores, vt + (size_t)b0 * PDIM * L_SEQ, ar + (size_t)b0 * PDIM,
        zb + (size_t)b0 * PDIM,
        L_SEQ, PDIM, L_SEQ, L_SEQ, L_SEQ, BATCH * PDIM,
        (size_t)L_SEQ * L_SEQ, (size_t)PDIM * L_SEQ, (size_t)PDIM, (size_t)PDIM, 3);
  }

  // GEMM3: out = (attn + residual) @ W3^T -> fp32 d_out, 8-wave kernel
  gemm_bt8<1, 0><<<dim3(DOUT / 128, MROWS / BM, 1), 512, 0, stream>>>(
      ar, w3b, out, PDIM, PDIM, PDIM, DOUT, 0, 0, 0);
}

// Round 17
// 178.346 us; speedup vs baseline: 1.1520x; 1.0011x over previous
//
#include <hip/hip_runtime.h>
#include <cstdint>
#include <cstddef>

#define L_SEQ 2048
#define BATCH 8
#define DIN   1024
#define PDIM  512
#define DOUT  1024
#define MROWS (L_SEQ * BATCH)   // 16384

typedef __attribute__((ext_vector_type(4))) float f32x4;
typedef __attribute__((ext_vector_type(8))) short bf16x8;

__device__ __forceinline__ unsigned short f2bf(float f) {
  union { float f; unsigned int u; } v; v.f = f;
  unsigned int u = v.u;
  unsigned int r = (u + 0x7FFFu + ((u >> 16) & 1u)) >> 16;
  return (unsigned short)r;
}
__device__ __forceinline__ float bf2f(unsigned short h) {
  union { unsigned int u; float f; } v; v.u = ((unsigned int)h) << 16;
  return v.f;
}

// async global->LDS, 16 bytes per lane; dest is wave-uniform base + lane*16
__device__ __forceinline__ void gld16(const unsigned short* g, unsigned short* l) {
  __builtin_amdgcn_global_load_lds(
      (const __attribute__((address_space(1))) void*)g,
      (__attribute__((address_space(3))) void*)l,
      16, 0, 0);
}

// T1: bijective XCD-chunked block remap (m204).
__device__ __forceinline__ int swz_lin(int lin, int nwg) {
  int q = nwg >> 3, r = nwg & 7;
  int xcd = lin & 7;
  int base = (xcd < r) ? xcd * (q + 1) : r * (q + 1) + (xcd - r) * q;
  return base + (lin >> 3);
}

// T2 LDS swizzle: logical 16B-chunk n of row r stored at position n ^ (r&7).
// gld16 path: swizzle folded into per-lane GLOBAL source col, linear LDS dest.
// Read side XORs the chunk index. Same involution everywhere (rule #21).

// merged convert for the three weight tensors (one launch)
__global__ void convert3_f32_bf16(const float* __restrict__ a, unsigned short* __restrict__ oa, int na4,
                                  const float* __restrict__ b, unsigned short* __restrict__ ob, int nb4,
                                  const float* __restrict__ c, unsigned short* __restrict__ oc, int nc4) {
  int total = na4 + nb4 + nc4;
  for (int i = blockIdx.x * blockDim.x + threadIdx.x; i < total;
       i += gridDim.x * blockDim.x) {
    const float* in; unsigned short* out; int j = i;
    if (j < na4)            { in = a; out = oa; }
    else if (j < na4 + nb4) { j -= na4; in = b; out = ob; }
    else                    { j -= na4 + nb4; in = c; out = oc; }
    float4 v = reinterpret_cast<const float4*>(in)[j];
    ushort4 o;
    o.x = f2bf(v.x); o.y = f2bf(v.y); o.z = f2bf(v.z); o.w = f2bf(v.w);
    reinterpret_cast<ushort4*>(out)[j] = o;
  }
}

// ---------------- V transpose: kv[l][b][512+p] -> vt[b][p][l] ----------------
__global__ void transpose_v_kernel(const unsigned short* __restrict__ kv,
                                   unsigned short* __restrict__ vt) {
  __shared__ unsigned short tile[32][33];
  int b = blockIdx.z;
  int l0 = blockIdx.x * 32;
  int p0 = blockIdx.y * 32;
  const unsigned short* src = kv + (size_t)b * (2 * PDIM) + PDIM;
  unsigned short* dst = vt + (size_t)b * PDIM * L_SEQ;
  int tx = threadIdx.x, ty = threadIdx.y;
  #pragma unroll
  for (int r = ty; r < 32; r += 8)
    tile[r][tx] = src[(size_t)(l0 + r) * (BATCH * 2 * PDIM) + p0 + tx];
  __syncthreads();
  #pragma unroll
  for (int r = ty; r < 32; r += 8)
    dst[(size_t)(p0 + r) * L_SEQ + l0 + tx] = tile[tx][r];
}

// ---------------- row softmax, causal — vectorized register-resident -------
__global__ void softmax_causal(unsigned short* __restrict__ S,
                               size_t strideB, float scale) {
  __shared__ float red[4];
  int b = blockIdx.z;
  int i = blockIdx.x;                       // causal row index
  unsigned short* row = S + b * strideB + (size_t)i * L_SEQ;
  int t = threadIdx.x;                      // 0..255
  int lane = t & 63, wid = t >> 6;          // 4 waves
  int e0 = t * 8;

  bf16x8 h = *(const bf16x8*)&row[e0];
  float v[8];
  float lmax = -3.0e38f;
  #pragma unroll
  for (int k = 0; k < 8; ++k) {
    float f = bf2f((unsigned short)h[k]) * scale;
    v[k] = (e0 + k <= i) ? f : -3.0e38f;
    lmax = fmaxf(lmax, v[k]);
  }
  #pragma unroll
  for (int o = 32; o > 0; o >>= 1) lmax = fmaxf(lmax, __shfl_xor(lmax, o));
  if (lane == 0) red[wid] = lmax;
  __syncthreads();
  float m = fmaxf(fmaxf(red[0], red[1]), fmaxf(red[2], red[3]));
  __syncthreads();                          // red reuse

  float lsum = 0.0f;
  #pragma unroll
  for (int k = 0; k < 8; ++k) {
    v[k] = __expf(v[k] - m);                // invalid lanes -> 0
    lsum += v[k];
  }
  #pragma unroll
  for (int o = 32; o > 0; o >>= 1) lsum += __shfl_xor(lsum, o);
  if (lane == 0) red[wid] = lsum;
  __syncthreads();
  float inv = 1.0f / (red[0] + red[1] + red[2] + red[3]);

  int jmax = ((i >> 7) + 1) << 7;           // PV's causal K-limit boundary
  if (e0 < jmax) {
    bf16x8 o8;
    #pragma unroll
    for (int k = 0; k < 8; ++k)
      o8[k] = (short)((e0 + k <= i) ? f2bf(v[k] * inv) : (unsigned short)0);
    *(bf16x8*)&row[e0] = o8;
  }
}

#define BM 128
#define BK 64

// ---------------- bf16 MFMA GEMM (512 thr / 8 waves): 128² tile ------------
// 2-phase dbuf + T1 + T2, 64KB LDS -> 2 blocks/CU, 16 waves/CU (4/SIMD).
// Wave (wm,wn) owns a 32x64 sub-tile. EPI: 0 bf16, 1 fp32. MODE: 0 plain,
// 1 causal lower-tri enumeration.
template<int EPI, int MODE>
__global__ __launch_bounds__(512)
void gemm_bt8(const unsigned short* __restrict__ A,
              const unsigned short* __restrict__ B,
              void* __restrict__ C,
              int K, int lda, int ldb, int ldc,
              size_t sAb, size_t sBb, size_t sCb) {
  int gx = gridDim.x, gy = gridDim.y;
  int nwg = gx * gy * (int)gridDim.z;
  int lin = ((int)blockIdx.z * gy + (int)blockIdx.y) * gx + (int)blockIdx.x;
  int wg = swz_lin(lin, nwg);
  int bx = wg % gx;
  int rem = wg / gx;
  int by = rem % gy;
  int bz = rem / gy;

  A += (size_t)bz * sAb;
  B += (size_t)bz * sBb;
  float* Cf = (float*)C + (size_t)bz * sCb;
  unsigned short* Ch = (unsigned short*)C + (size_t)bz * sCb;

  __shared__ unsigned short As[2][BM * BK];
  __shared__ unsigned short Bs[2][BM * BK];

  int t = threadIdx.x;
  int lane = t & 63;
  int wid = t >> 6;                           // 0..7
  int wm = wid >> 1;                          // rows wm*32
  int wn = wid & 1;                           // cols wn*64
  int lr = lane & 15;
  int kof = (lane >> 4) * 8;
  int srow = lane >> 3;
  int scol = ((lane & 7) ^ srow) * 8;         // T2 pre-swizzled global col
  int rxor = (lane & 7) << 3;                 // T2 read-side XOR

  int tmTile, tnBase;
  if (MODE == 1) {
    int t3 = bx;
    int tm3 = 0;
    while ((tm3 + 1) * (tm3 + 2) / 2 <= t3) tm3++;
    tmTile = tm3;
    tnBase = (t3 - tm3 * (tm3 + 1) / 2) * 128;
  } else {
    tmTile = by;
    tnBase = bx * 128;
  }
  int tm = tmTile * BM;
  int nk = K / BK;

  f32x4 acc[2][4];
  f32x4 zero = {0.0f, 0.0f, 0.0f, 0.0f};
  #pragma unroll
  for (int m = 0; m < 2; ++m)
    #pragma unroll
    for (int n = 0; n < 4; ++n) acc[m][n] = zero;

  auto stage = [&](int bi, int ks) {
    int k0 = ks * BK;
    #pragma unroll
    for (int it = 0; it < 2; ++it) {
      int r = it * 64 + wid * 8;
      gld16(A + (size_t)(tm + r + srow) * lda + k0 + scol, &As[bi][r * BK]);
    }
    #pragma unroll
    for (int it = 0; it < 2; ++it) {
      int r = it * 64 + wid * 8;
      gld16(B + (size_t)(tnBase + r + srow) * ldb + k0 + scol, &Bs[bi][r * BK]);
    }
  };

  stage(0, 0);
  for (int ks = 0; ks < nk; ++ks) {
    int bi = ks & 1;
    if (ks + 1 < nk) {
      stage(bi ^ 1, ks + 1);
      asm volatile("s_waitcnt vmcnt(4)" ::: "memory");
    } else {
      asm volatile("s_waitcnt vmcnt(0)" ::: "memory");
    }
    __builtin_amdgcn_s_barrier();
    __builtin_amdgcn_sched_barrier(0);

    #pragma unroll
    for (int kk = 0; kk < BK; kk += 32) {
      bf16x8 af[2], bfr[4];
      #pragma unroll
      for (int m = 0; m < 2; ++m)
        af[m] = *(const bf16x8*)&As[bi][(wm * 32 + m * 16 + lr) * BK + ((kk + kof) ^ rxor)];
      #pragma unroll
      for (int n = 0; n < 4; ++n)
        bfr[n] = *(const bf16x8*)&Bs[bi][(wn * 64 + n * 16 + lr) * BK + ((kk + kof) ^ rxor)];
      #pragma unroll
      for (int m = 0; m < 2; ++m)
        #pragma unroll
        for (int n = 0; n < 4; ++n)
          acc[m][n] = __builtin_amdgcn_mfma_f32_16x16x32_bf16(af[m], bfr[n], acc[m][n], 0, 0, 0);
    }
    asm volatile("" ::: "memory");
    __builtin_amdgcn_s_barrier();
    __builtin_amdgcn_sched_barrier(0);
  }

  int rb0 = tm + wm * 32 + (lane >> 4) * 4;   // C/D: col=lane&15, row=(lane>>4)*4+j
  #pragma unroll
  for (int m = 0; m < 2; ++m) {
    #pragma unroll
    for (int n = 0; n < 4; ++n) {
      int col = tnBase + wn * 64 + n * 16 + lr;
      #pragma unroll
      for (int j = 0; j < 4; ++j) {
        int row = rb0 + m * 16 + j;
        float v = acc[m][n][j];
        size_t idx = (size_t)row * ldc + col;
        if constexpr (EPI == 1) Cf[idx] = v;
        else                    Ch[idx] = f2bf(v);
      }
    }
  }
}

// ---------------- PV GEMM (512 thr / 8 waves): 128x64 tile, causal ---------
// TBN=64, 48KB LDS -> 3 blocks/CU (24 waves/CU). Wave = 32x32 sub-tile.
// Causal K-limit, rows descending in work; bf16 out + residual add.
__global__ __launch_bounds__(512)
void gemm_pv8(const unsigned short* __restrict__ A,
              const unsigned short* __restrict__ B,
              unsigned short* __restrict__ C,
              const unsigned short* __restrict__ R,
              int M, int K, int lda, int ldb, int ldc,
              size_t sAb, size_t sBb, size_t sCb, size_t sRb) {
  int gx = gridDim.x, gy = gridDim.y;
  int nwg = gx * gy * (int)gridDim.z;
  int lin = ((int)blockIdx.z * gy + (int)blockIdx.y) * gx + (int)blockIdx.x;
  int wg = swz_lin(lin, nwg);
  int bx = wg % gx;
  int rem = wg / gx;
  int by = rem % gy;
  int bz = rem / gy;

  A += (size_t)bz * sAb;
  B += (size_t)bz * sBb;
  R += (size_t)bz * sRb;
  C += (size_t)bz * sCb;

  __shared__ unsigned short As[2][BM * BK];
  __shared__ unsigned short Bs[2][64 * BK];

  int t = threadIdx.x;
  int lane = t & 63;
  int wid = t >> 6;                           // 0..7
  int wm = wid >> 1;                          // rows wm*32
  int wn = wid & 1;                           // cols wn*32
  int lr = lane & 15;
  int kof = (lane >> 4) * 8;
  int srow = lane >> 3;
  int scol = ((lane & 7) ^ srow) * 8;
  int rxor = (lane & 7) << 3;

  int tmTile = (M / BM - 1) - by;             // descending work order
  int tnBase = bx * 64;
  int tm = tmTile * BM;
  int kEnd = (tm + BM) < K ? (tm + BM) : K;
  int nk = kEnd / BK;

  f32x4 acc[2][2];
  f32x4 zero = {0.0f, 0.0f, 0.0f, 0.0f};
  #pragma unroll
  for (int m = 0; m < 2; ++m)
    #pragma unroll
    for (int n = 0; n < 2; ++n) acc[m][n] = zero;

  auto stage = [&](int bi, int ks) {
    int k0 = ks * BK;
    #pragma unroll
    for (int it = 0; it < 2; ++it) {
      int r = it * 64 + wid * 8;
      gld16(A + (size_t)(tm + r + srow) * lda + k0 + scol, &As[bi][r * BK]);
    }
    {
      int r = wid * 8;
      gld16(B + (size_t)(tnBase + r + srow) * ldb + k0 + scol, &Bs[bi][r * BK]);
    }
  };

  stage(0, 0);
  for (int ks = 0; ks < nk; ++ks) {
    int bi = ks & 1;
    if (ks + 1 < nk) {
      stage(bi ^ 1, ks + 1);
      asm volatile("s_waitcnt vmcnt(3)" ::: "memory");
    } else {
      asm volatile("s_waitcnt vmcnt(0)" ::: "memory");
    }
    __builtin_amdgcn_s_barrier();
    __builtin_amdgcn_sched_barrier(0);

    #pragma unroll
    for (int kk = 0; kk < BK; kk += 32) {
      bf16x8 af[2], bfr[2];
      #pragma unroll
      for (int m = 0; m < 2; ++m)
        af[m] = *(const bf16x8*)&As[bi][(wm * 32 + m * 16 + lr) * BK + ((kk + kof) ^ rxor)];
      #pragma unroll
      for (int n = 0; n < 2; ++n)
        bfr[n] = *(const bf16x8*)&Bs[bi][(wn * 32 + n * 16 + lr) * BK + ((kk + kof) ^ rxor)];
      #pragma unroll
      for (int m = 0; m < 2; ++m)
        #pragma unroll
        for (int n = 0; n < 2; ++n)
          acc[m][n] = __builtin_amdgcn_mfma_f32_16x16x32_bf16(af[m], bfr[n], acc[m][n], 0, 0, 0);
    }
    asm volatile("" ::: "memory");
    __builtin_amdgcn_s_barrier();
    __builtin_amdgcn_sched_barrier(0);
  }

  int rb0 = tm + wm * 32 + (lane >> 4) * 4;
  #pragma unroll
  for (int m = 0; m < 2; ++m) {
    #pragma unroll
    for (int n = 0; n < 2; ++n) {
      int col = tnBase + wn * 32 + n * 16 + lr;
      #pragma unroll
      for (int j = 0; j < 4; ++j) {
        int row = rb0 + m * 16 + j;
        size_t idx = (size_t)row * ldc + col;
        C[idx] = f2bf(acc[m][n][j] + bf2f(R[idx]));
      }
    }
  }
}

// ---------------- GEMM1 fused (512 thr / 8 waves): fp32 A x bf16 B^T -------
// A reg-staged (2 slots x 2 float4 -> cvt -> ds_write_b128), B via gld16.
// Same T2-swizzled LDS content as the gld16 path. 128² tile, mode 0.
__global__ __launch_bounds__(512)
void gemm_a32_8(const float* __restrict__ A,
                const unsigned short* __restrict__ B,
                unsigned short* __restrict__ C,
                int K, int lda, int ldb, int ldc) {
  int gx = gridDim.x, gy = gridDim.y;
  int nwg = gx * gy;
  int lin = (int)blockIdx.y * gx + (int)blockIdx.x;
  int wg = swz_lin(lin, nwg);
  int bx = wg % gx;
  int by = wg / gx;

  __shared__ unsigned short As[2][BM * BK];
  __shared__ unsigned short Bs[2][BM * BK];

  int t = threadIdx.x;
  int lane = t & 63;
  int wid = t >> 6;
  int wm = wid >> 1;
  int wn = wid & 1;
  int lr = lane & 15;
  int kof = (lane >> 4) * 8;
  int srow = lane >> 3;
  int scol = ((lane & 7) ^ srow) * 8;
  int rxor = (lane & 7) << 3;

  int tm = by * BM;
  int tnBase = bx * 128;
  int nk = K / BK;

  f32x4 acc[2][4];
  f32x4 zero = {0.0f, 0.0f, 0.0f, 0.0f};
  #pragma unroll
  for (int m = 0; m < 2; ++m)
    #pragma unroll
    for (int n = 0; n < 4; ++n) acc[m][n] = zero;

  float4 ar[2][2];                            // in-flight A (2 slots x 8 fp32)

  auto loadA = [&](int ks) {
    int k0 = ks * BK;
    #pragma unroll
    for (int it = 0; it < 2; ++it) {
      int r = it * 64 + wid * 8;
      const float4* p = reinterpret_cast<const float4*>(
          A + (size_t)(tm + r + srow) * lda + k0 + scol);
      ar[it][0] = p[0];
      ar[it][1] = p[1];
    }
  };
  auto writeA = [&](int bi) {
    #pragma unroll
    for (int it = 0; it < 2; ++it) {
      int r = it * 64 + wid * 8;
      bf16x8 h;
      h[0] = (short)f2bf(ar[it][0].x); h[1] = (short)f2bf(ar[it][0].y);
      h[2] = (short)f2bf(ar[it][0].z); h[3] = (short)f2bf(ar[it][0].w);
      h[4] = (short)f2bf(ar[it][1].x); h[5] = (short)f2bf(ar[it][1].y);
      h[6] = (short)f2bf(ar[it][1].z); h[7] = (short)f2bf(ar[it][1].w);
      *(bf16x8*)&As[bi][(r + srow) * BK + (lane & 7) * 8] = h;
    }
  };
  auto stageB = [&](int bi, int ks) {
    int k0 = ks * BK;
    #pragma unroll
    for (int it = 0; it < 2; ++it) {
      int r = it * 64 + wid * 8;
      gld16(B + (size_t)(tnBase + r + srow) * ldb + k0 + scol, &Bs[bi][r * BK]);
    }
  };

  loadA(0);
  stageB(0, 0);
  writeA(0);                                  // compiler waits the A regs

  for (int ks = 0; ks < nk; ++ks) {
    int bi = ks & 1;
    if (ks + 1 < nk) {
      loadA(ks + 1);                          // 4 vm ops
      stageB(bi ^ 1, ks + 1);                 // 2 vm ops
      asm volatile("s_waitcnt vmcnt(6)" ::: "memory");  // current B done
    } else {
      asm volatile("s_waitcnt vmcnt(0)" ::: "memory");
    }
    asm volatile("s_waitcnt lgkmcnt(0)" ::: "memory");  // ds_writes drained
    __builtin_amdgcn_s_barrier();
    __builtin_amdgcn_sched_barrier(0);

    #pragma unroll
    for (int kk = 0; kk < BK; kk += 32) {
      bf16x8 af[2], bfr[4];
      #pragma unroll
      for (int m = 0; m < 2; ++m)
        af[m] = *(const bf16x8*)&As[bi][(wm * 32 + m * 16 + lr) * BK + ((kk + kof) ^ rxor)];
      #pragma unroll
      for (int n = 0; n < 4; ++n)
        bfr[n] = *(const bf16x8*)&Bs[bi][(wn * 64 + n * 16 + lr) * BK + ((kk + kof) ^ rxor)];
      #pragma unroll
      for (int m = 0; m < 2; ++m)
        #pragma unroll
        for (int n = 0; n < 4; ++n)
          acc[m][n] = __builtin_amdgcn_mfma_f32_16x16x32_bf16(af[m], bfr[n], acc[m][n], 0, 0, 0);
    }
    if (ks + 1 < nk) writeA(bi ^ 1);          // cvt+ds_write under MFMA tail
    asm volatile("" ::: "memory");
    __builtin_amdgcn_s_barrier();
    __builtin_amdgcn_sched_barrier(0);
  }

  int rb0 = tm + wm * 32 + (lane >> 4) * 4;
  #pragma unroll
  for (int m = 0; m < 2; ++m) {
    #pragma unroll
    for (int n = 0; n < 4; ++n) {
      int col = tnBase + wn * 64 + n * 16 + lr;
      #pragma unroll
      for (int j = 0; j < 4; ++j) {
        int row = rb0 + m * 16 + j;
        C[(size_t)row * ldc + col] = f2bf(acc[m][n][j]);
      }
    }
  }
}

// ---------------- fallback sentinel ----------------
__global__ void fill_kernel(float* out, int n, float v) {
  int i = blockIdx.x * blockDim.x + threadIdx.x;
  for (; i < n; i += gridDim.x * blockDim.x) out[i] = v;
}

extern "C" void kernel_launch(void* const* d_in, const int* in_sizes, int n_in,
                              void* d_out, int out_size, void* d_ws, size_t ws_size,
                              hipStream_t stream) {
  const float* x  = (const float*)d_in[0];
  const float* W1 = (const float*)d_in[1];
  const float* W2 = (const float*)d_in[2];
  const float* W3 = (const float*)d_in[3];
  float* out = (float*)d_out;

  char* ws = (char*)d_ws;
  size_t off = 0;
  auto alloc = [&](size_t bytes) -> char* {
    char* p = ws + off;
    off += (bytes + 255) & ~(size_t)255;
    return p;
  };

  unsigned short* zb  = (unsigned short*)alloc((size_t)MROWS * PDIM * 2);
  unsigned short* kvb = (unsigned short*)alloc((size_t)MROWS * 2 * PDIM * 2);
  unsigned short* vt  = (unsigned short*)alloc((size_t)BATCH * PDIM * L_SEQ * 2);
  unsigned short* ar  = (unsigned short*)alloc((size_t)MROWS * PDIM * 2);
  unsigned short* w3b = (unsigned short*)alloc((size_t)DOUT * PDIM * 2);
  size_t persist = off;

  char* scratch = ws + persist;
  size_t avail = (ws_size > persist) ? (ws_size - persist) : 0;

  size_t w1B  = ((size_t)PDIM * DIN * 2 + 255) & ~(size_t)255;
  size_t w2B  = ((size_t)2 * PDIM * PDIM * 2 + 255) & ~(size_t)255;
  size_t convNeed = w1B + w2B;

  size_t scores1 = ((size_t)L_SEQ * L_SEQ * 2 + 255) & ~(size_t)255; // 8MB bf16
  size_t per = scores1;

  if (avail < convNeed || avail < per) {
    float sentinel = 1.0e6f + (float)(ws_size >> 20);
    fill_kernel<<<512, 256, 0, stream>>>(out, out_size, sentinel);
    return;
  }

  int c = (int)(avail / per);
  if (c > BATCH) c = BATCH;
  int nch = (BATCH + c - 1) / c;
  c = (BATCH + nch - 1) / nch;

  unsigned short* w1b = (unsigned short*)(scratch);
  unsigned short* w2b = (unsigned short*)(scratch + w1B);
  unsigned short* scores = (unsigned short*)(scratch);  // overlaps w1b/w2b (consumed)

  const float scaling = 0.04419417382415922f;  // 512^-0.5
  const int NTRI = (L_SEQ / BM) * (L_SEQ / BM + 1) / 2;   // 136 lower-tri tiles

  // weights convert (one launch); x is consumed fp32 directly by gemm_a32_8
  convert3_f32_bf16<<<768, 256, 0, stream>>>(
      W1, w1b, (PDIM * DIN) / 4,
      W2, w2b, (2 * PDIM * PDIM) / 4,
      W3, w3b, (DOUT * PDIM) / 4);

  // GEMM1 (fused cvt, 8-wave): z = x @ W1^T
  gemm_a32_8<<<dim3(PDIM / 128, MROWS / BM, 1), 512, 0, stream>>>(
      x, w1b, zb, DIN, DIN, DIN, PDIM);

  // GEMM2: kv = z @ W2^T (8-wave)
  gemm_bt8<0, 0><<<dim3(2 * PDIM / 128, MROWS / BM, 1), 512, 0, stream>>>(
      zb, w2b, kvb, PDIM, PDIM, PDIM, 2 * PDIM, 0, 0, 0);

  // V transpose per batch: vt[b][p][l]
  transpose_v_kernel<<<dim3(L_SEQ / 32, PDIM / 32, BATCH), dim3(32, 8), 0, stream>>>(kvb, vt);

  // ---- chunked attention (c==8 expected: single pass) ----
  for (int b0 = 0; b0 < BATCH; b0 += c) {
    int cb = (BATCH - b0 < c) ? (BATCH - b0) : c;

    // scores[z] = Q @ K^T (bf16), triangular tiles (8-wave)
    gemm_bt8<0, 1><<<dim3(NTRI, 1, cb), 512, 0, stream>>>(
        zb + (size_t)b0 * PDIM, kvb + (size_t)b0 * 2 * PDIM, scores,
        PDIM, BATCH * PDIM, BATCH * 2 * PDIM, L_SEQ,
        (size_t)PDIM, (size_t)2 * PDIM, (size_t)L_SEQ * L_SEQ);

    softmax_causal<<<dim3(L_SEQ, 1, cb), 256, 0, stream>>>(
        scores, (size_t)L_SEQ * L_SEQ, scaling);

    // attn_out + residual -> ar (bf16): 8-wave PV, causal, rows descending
    gemm_pv8<<<dim3(PDIM / 64, L_SEQ / BM, cb), 512, 0, stream>>>(
        scores, vt + (size_t)b0 * PDIM * L_SEQ, ar + (size_t)b0 * PDIM,
        zb + (size_t)b0 * PDIM,
        L_SEQ, L_SEQ, L_SEQ, L_SEQ, BATCH * PDIM,
        (size_t)L_SEQ * L_SEQ, (size_t)PDIM * L_SEQ, (size_t)PDIM, (size_t)PDIM);
  }

  // GEMM3: out = (attn + residual) @ W3^T -> fp32 (8-wave)
  gemm_bt8<1, 0><<<dim3(DOUT / 128, MROWS / BM, 1), 512, 0, stream>>>(
      ar, w3b, out, PDIM, PDIM, PDIM, DOUT, 0, 0, 0);
}

// Round 18
// 176.189 us; speedup vs baseline: 1.1661x; 1.0122x over previous
//
#include <hip/hip_runtime.h>
#include <cstdint>
#include <cstddef>

#define L_SEQ 2048
#define BATCH 8
#define DIN   1024
#define PDIM  512
#define DOUT  1024
#define MROWS (L_SEQ * BATCH)   // 16384

typedef __attribute__((ext_vector_type(4))) float f32x4;
typedef __attribute__((ext_vector_type(8))) short bf16x8;

__device__ __forceinline__ unsigned short f2bf(float f) {
  union { float f; unsigned int u; } v; v.f = f;
  unsigned int u = v.u;
  unsigned int r = (u + 0x7FFFu + ((u >> 16) & 1u)) >> 16;
  return (unsigned short)r;
}
__device__ __forceinline__ float bf2f(unsigned short h) {
  union { unsigned int u; float f; } v; v.u = ((unsigned int)h) << 16;
  return v.f;
}

// async global->LDS, 16 bytes per lane; dest is wave-uniform base + lane*16
__device__ __forceinline__ void gld16(const unsigned short* g, unsigned short* l) {
  __builtin_amdgcn_global_load_lds(
      (const __attribute__((address_space(1))) void*)g,
      (__attribute__((address_space(3))) void*)l,
      16, 0, 0);
}

// T1: bijective XCD-chunked block remap (m204).
__device__ __forceinline__ int swz_lin(int lin, int nwg) {
  int q = nwg >> 3, r = nwg & 7;
  int xcd = lin & 7;
  int base = (xcd < r) ? xcd * (q + 1) : r * (q + 1) + (xcd - r) * q;
  return base + (lin >> 3);
}

// T2 LDS swizzle: logical 16B-chunk n of row r stored at position n ^ (r&7).
// gld16 path: swizzle folded into per-lane GLOBAL source col, linear LDS dest.
// Read side XORs the chunk index. Same involution everywhere (rule #21).

// merged convert for the three weight tensors (one launch)
__global__ void convert3_f32_bf16(const float* __restrict__ a, unsigned short* __restrict__ oa, int na4,
                                  const float* __restrict__ b, unsigned short* __restrict__ ob, int nb4,
                                  const float* __restrict__ c, unsigned short* __restrict__ oc, int nc4) {
  int total = na4 + nb4 + nc4;
  for (int i = blockIdx.x * blockDim.x + threadIdx.x; i < total;
       i += gridDim.x * blockDim.x) {
    const float* in; unsigned short* out; int j = i;
    if (j < na4)            { in = a; out = oa; }
    else if (j < na4 + nb4) { j -= na4; in = b; out = ob; }
    else                    { j -= na4 + nb4; in = c; out = oc; }
    float4 v = reinterpret_cast<const float4*>(in)[j];
    ushort4 o;
    o.x = f2bf(v.x); o.y = f2bf(v.y); o.z = f2bf(v.z); o.w = f2bf(v.w);
    reinterpret_cast<ushort4*>(out)[j] = o;
  }
}

// ---------------- V transpose: kv[l][b][512+p] -> vt[b][p][l] ----------------
__global__ void transpose_v_kernel(const unsigned short* __restrict__ kv,
                                   unsigned short* __restrict__ vt) {
  __shared__ unsigned short tile[32][33];
  int b = blockIdx.z;
  int l0 = blockIdx.x * 32;
  int p0 = blockIdx.y * 32;
  const unsigned short* src = kv + (size_t)b * (2 * PDIM) + PDIM;
  unsigned short* dst = vt + (size_t)b * PDIM * L_SEQ;
  int tx = threadIdx.x, ty = threadIdx.y;
  #pragma unroll
  for (int r = ty; r < 32; r += 8)
    tile[r][tx] = src[(size_t)(l0 + r) * (BATCH * 2 * PDIM) + p0 + tx];
  __syncthreads();
  #pragma unroll
  for (int r = ty; r < 32; r += 8)
    dst[(size_t)(p0 + r) * L_SEQ + l0 + tx] = tile[tx][r];
}

// ---------------- row softmax, causal — vectorized register-resident -------
__global__ void softmax_causal(unsigned short* __restrict__ S,
                               size_t strideB, float scale) {
  __shared__ float red[4];
  int b = blockIdx.z;
  int i = blockIdx.x;                       // causal row index
  unsigned short* row = S + b * strideB + (size_t)i * L_SEQ;
  int t = threadIdx.x;                      // 0..255
  int lane = t & 63, wid = t >> 6;          // 4 waves
  int e0 = t * 8;

  bf16x8 h = *(const bf16x8*)&row[e0];
  float v[8];
  float lmax = -3.0e38f;
  #pragma unroll
  for (int k = 0; k < 8; ++k) {
    float f = bf2f((unsigned short)h[k]) * scale;
    v[k] = (e0 + k <= i) ? f : -3.0e38f;
    lmax = fmaxf(lmax, v[k]);
  }
  #pragma unroll
  for (int o = 32; o > 0; o >>= 1) lmax = fmaxf(lmax, __shfl_xor(lmax, o));
  if (lane == 0) red[wid] = lmax;
  __syncthreads();
  float m = fmaxf(fmaxf(red[0], red[1]), fmaxf(red[2], red[3]));
  __syncthreads();                          // red reuse

  float lsum = 0.0f;
  #pragma unroll
  for (int k = 0; k < 8; ++k) {
    v[k] = __expf(v[k] - m);                // invalid lanes -> 0
    lsum += v[k];
  }
  #pragma unroll
  for (int o = 32; o > 0; o >>= 1) lsum += __shfl_xor(lsum, o);
  if (lane == 0) red[wid] = lsum;
  __syncthreads();
  float inv = 1.0f / (red[0] + red[1] + red[2] + red[3]);

  int jmax = ((i >> 7) + 1) << 7;           // PV's causal K-limit boundary
  if (e0 < jmax) {
    bf16x8 o8;
    #pragma unroll
    for (int k = 0; k < 8; ++k)
      o8[k] = (short)((e0 + k <= i) ? f2bf(v[k] * inv) : (unsigned short)0);
    *(bf16x8*)&row[e0] = o8;
  }
}

#define BM 128
#define BK 64

// ---------------- bf16 MFMA GEMM (512 thr / 8 waves): 128² tile ------------
// 2-phase dbuf + T1 + T2, 64KB LDS -> 2 blocks/CU, 16 waves/CU (4/SIMD).
// Wave (wm,wn) owns a 32x64 sub-tile. EPI: 0 bf16, 1 fp32. MODE: 0 plain,
// 1 causal lower-tri enumeration.
template<int EPI, int MODE>
__global__ __launch_bounds__(512)
void gemm_bt8(const unsigned short* __restrict__ A,
              const unsigned short* __restrict__ B,
              void* __restrict__ C,
              int K, int lda, int ldb, int ldc,
              size_t sAb, size_t sBb, size_t sCb) {
  int gx = gridDim.x, gy = gridDim.y;
  int nwg = gx * gy * (int)gridDim.z;
  int lin = ((int)blockIdx.z * gy + (int)blockIdx.y) * gx + (int)blockIdx.x;
  int wg = swz_lin(lin, nwg);
  int bx = wg % gx;
  int rem = wg / gx;
  int by = rem % gy;
  int bz = rem / gy;

  A += (size_t)bz * sAb;
  B += (size_t)bz * sBb;
  float* Cf = (float*)C + (size_t)bz * sCb;
  unsigned short* Ch = (unsigned short*)C + (size_t)bz * sCb;

  __shared__ unsigned short As[2][BM * BK];
  __shared__ unsigned short Bs[2][BM * BK];

  int t = threadIdx.x;
  int lane = t & 63;
  int wid = t >> 6;                           // 0..7
  int wm = wid >> 1;                          // rows wm*32
  int wn = wid & 1;                           // cols wn*64
  int lr = lane & 15;
  int kof = (lane >> 4) * 8;
  int srow = lane >> 3;
  int scol = ((lane & 7) ^ srow) * 8;         // T2 pre-swizzled global col
  int rxor = (lane & 7) << 3;                 // T2 read-side XOR

  int tmTile, tnBase;
  if (MODE == 1) {
    int t3 = bx;
    int tm3 = 0;
    while ((tm3 + 1) * (tm3 + 2) / 2 <= t3) tm3++;
    tmTile = tm3;
    tnBase = (t3 - tm3 * (tm3 + 1) / 2) * 128;
  } else {
    tmTile = by;
    tnBase = bx * 128;
  }
  int tm = tmTile * BM;
  int nk = K / BK;

  f32x4 acc[2][4];
  f32x4 zero = {0.0f, 0.0f, 0.0f, 0.0f};
  #pragma unroll
  for (int m = 0; m < 2; ++m)
    #pragma unroll
    for (int n = 0; n < 4; ++n) acc[m][n] = zero;

  auto stage = [&](int bi, int ks) {
    int k0 = ks * BK;
    #pragma unroll
    for (int it = 0; it < 2; ++it) {
      int r = it * 64 + wid * 8;
      gld16(A + (size_t)(tm + r + srow) * lda + k0 + scol, &As[bi][r * BK]);
    }
    #pragma unroll
    for (int it = 0; it < 2; ++it) {
      int r = it * 64 + wid * 8;
      gld16(B + (size_t)(tnBase + r + srow) * ldb + k0 + scol, &Bs[bi][r * BK]);
    }
  };

  stage(0, 0);
  for (int ks = 0; ks < nk; ++ks) {
    int bi = ks & 1;
    if (ks + 1 < nk) {
      stage(bi ^ 1, ks + 1);
      asm volatile("s_waitcnt vmcnt(4)" ::: "memory");
    } else {
      asm volatile("s_waitcnt vmcnt(0)" ::: "memory");
    }
    __builtin_amdgcn_s_barrier();
    __builtin_amdgcn_sched_barrier(0);

    #pragma unroll
    for (int kk = 0; kk < BK; kk += 32) {
      bf16x8 af[2], bfr[4];
      #pragma unroll
      for (int m = 0; m < 2; ++m)
        af[m] = *(const bf16x8*)&As[bi][(wm * 32 + m * 16 + lr) * BK + ((kk + kof) ^ rxor)];
      #pragma unroll
      for (int n = 0; n < 4; ++n)
        bfr[n] = *(const bf16x8*)&Bs[bi][(wn * 64 + n * 16 + lr) * BK + ((kk + kof) ^ rxor)];
      #pragma unroll
      for (int m = 0; m < 2; ++m)
        #pragma unroll
        for (int n = 0; n < 4; ++n)
          acc[m][n] = __builtin_amdgcn_mfma_f32_16x16x32_bf16(af[m], bfr[n], acc[m][n], 0, 0, 0);
    }
    asm volatile("" ::: "memory");
    __builtin_amdgcn_s_barrier();
    __builtin_amdgcn_sched_barrier(0);
  }

  int rb0 = tm + wm * 32 + (lane >> 4) * 4;   // C/D: col=lane&15, row=(lane>>4)*4+j
  #pragma unroll
  for (int m = 0; m < 2; ++m) {
    #pragma unroll
    for (int n = 0; n < 4; ++n) {
      int col = tnBase + wn * 64 + n * 16 + lr;
      #pragma unroll
      for (int j = 0; j < 4; ++j) {
        int row = rb0 + m * 16 + j;
        float v = acc[m][n][j];
        size_t idx = (size_t)row * ldc + col;
        if constexpr (EPI == 1) Cf[idx] = v;
        else                    Ch[idx] = f2bf(v);
      }
    }
  }
}

// ---------------- PV GEMM (512 thr / 8 waves): 128x64 tile, causal ---------
// TBN=64, 48KB LDS -> 3 blocks/CU (24 waves/CU). Wave = 32x32 sub-tile.
// Causal K-limit, rows descending in work; bf16 out + residual add.
__global__ __launch_bounds__(512)
void gemm_pv8(const unsigned short* __restrict__ A,
              const unsigned short* __restrict__ B,
              unsigned short* __restrict__ C,
              const unsigned short* __restrict__ R,
              int M, int K, int lda, int ldb, int ldc,
              size_t sAb, size_t sBb, size_t sCb, size_t sRb) {
  int gx = gridDim.x, gy = gridDim.y;
  int nwg = gx * gy * (int)gridDim.z;
  int lin = ((int)blockIdx.z * gy + (int)blockIdx.y) * gx + (int)blockIdx.x;
  int wg = swz_lin(lin, nwg);
  int bx = wg % gx;
  int rem = wg / gx;
  int by = rem % gy;
  int bz = rem / gy;

  A += (size_t)bz * sAb;
  B += (size_t)bz * sBb;
  R += (size_t)bz * sRb;
  C += (size_t)bz * sCb;

  __shared__ unsigned short As[2][BM * BK];
  __shared__ unsigned short Bs[2][64 * BK];

  int t = threadIdx.x;
  int lane = t & 63;
  int wid = t >> 6;                           // 0..7
  int wm = wid >> 1;                          // rows wm*32
  int wn = wid & 1;                           // cols wn*32
  int lr = lane & 15;
  int kof = (lane >> 4) * 8;
  int srow = lane >> 3;
  int scol = ((lane & 7) ^ srow) * 8;
  int rxor = (lane & 7) << 3;

  int tmTile = (M / BM - 1) - by;             // descending work order
  int tnBase = bx * 64;
  int tm = tmTile * BM;
  int kEnd = (tm + BM) < K ? (tm + BM) : K;
  int nk = kEnd / BK;

  f32x4 acc[2][2];
  f32x4 zero = {0.0f, 0.0f, 0.0f, 0.0f};
  #pragma unroll
  for (int m = 0; m < 2; ++m)
    #pragma unroll
    for (int n = 0; n < 2; ++n) acc[m][n] = zero;

  auto stage = [&](int bi, int ks) {
    int k0 = ks * BK;
    #pragma unroll
    for (int it = 0; it < 2; ++it) {
      int r = it * 64 + wid * 8;
      gld16(A + (size_t)(tm + r + srow) * lda + k0 + scol, &As[bi][r * BK]);
    }
    {
      int r = wid * 8;
      gld16(B + (size_t)(tnBase + r + srow) * ldb + k0 + scol, &Bs[bi][r * BK]);
    }
  };

  stage(0, 0);
  for (int ks = 0; ks < nk; ++ks) {
    int bi = ks & 1;
    if (ks + 1 < nk) {
      stage(bi ^ 1, ks + 1);
      asm volatile("s_waitcnt vmcnt(3)" ::: "memory");
    } else {
      asm volatile("s_waitcnt vmcnt(0)" ::: "memory");
    }
    __builtin_amdgcn_s_barrier();
    __builtin_amdgcn_sched_barrier(0);

    #pragma unroll
    for (int kk = 0; kk < BK; kk += 32) {
      bf16x8 af[2], bfr[2];
      #pragma unroll
      for (int m = 0; m < 2; ++m)
        af[m] = *(const bf16x8*)&As[bi][(wm * 32 + m * 16 + lr) * BK + ((kk + kof) ^ rxor)];
      #pragma unroll
      for (int n = 0; n < 2; ++n)
        bfr[n] = *(const bf16x8*)&Bs[bi][(wn * 32 + n * 16 + lr) * BK + ((kk + kof) ^ rxor)];
      #pragma unroll
      for (int m = 0; m < 2; ++m)
        #pragma unroll
        for (int n = 0; n < 2; ++n)
          acc[m][n] = __builtin_amdgcn_mfma_f32_16x16x32_bf16(af[m], bfr[n], acc[m][n], 0, 0, 0);
    }
    asm volatile("" ::: "memory");
    __builtin_amdgcn_s_barrier();
    __builtin_amdgcn_sched_barrier(0);
  }

  int rb0 = tm + wm * 32 + (lane >> 4) * 4;
  #pragma unroll
  for (int m = 0; m < 2; ++m) {
    #pragma unroll
    for (int n = 0; n < 2; ++n) {
      int col = tnBase + wn * 32 + n * 16 + lr;
      #pragma unroll
      for (int j = 0; j < 4; ++j) {
        int row = rb0 + m * 16 + j;
        size_t idx = (size_t)row * ldc + col;
        C[idx] = f2bf(acc[m][n][j] + bf2f(R[idx]));
      }
    }
  }
}

// ---------------- GEMM1 fused (256 thr / 4 waves): fp32 A x bf16 B^T -------
// R15/R16-measured best for this shape. A reg-staged (4 slots x 2 float4 ->
// cvt -> ds_write_b128), B via gld16. T2-swizzled LDS content. 128² tile.
__global__ __launch_bounds__(256)
void gemm_a32(const float* __restrict__ A,
              const unsigned short* __restrict__ B,
              unsigned short* __restrict__ C,
              int K, int lda, int ldb, int ldc) {
  int gx = gridDim.x, gy = gridDim.y;
  int nwg = gx * gy;
  int lin = (int)blockIdx.y * gx + (int)blockIdx.x;
  int wg = swz_lin(lin, nwg);
  int bx = wg % gx;
  int by = wg / gx;

  __shared__ unsigned short As[2][BM * BK];
  __shared__ unsigned short Bs[2][BM * BK];   // TBN=128

  int t = threadIdx.x;
  int lane = t & 63;
  int wid = t >> 6;
  int wr = (wid >> 1) * 64;
  int wc = (wid & 1) * 64;
  int lr = lane & 15;
  int kof = (lane >> 4) * 8;
  int srow = lane >> 3;
  int scol = ((lane & 7) ^ srow) * 8;         // T2 pre-swizzled global col
  int rxor = (lane & 7) << 3;

  int tm = by * BM;
  int tnBase = bx * 128;
  int nk = K / BK;

  f32x4 acc[4][4];
  f32x4 zero = {0.0f, 0.0f, 0.0f, 0.0f};
  #pragma unroll
  for (int m = 0; m < 4; ++m)
    #pragma unroll
    for (int n = 0; n < 4; ++n) acc[m][n] = zero;

  float4 ar[4][2];                            // in-flight A tile

  auto loadA = [&](int ks) {
    int k0 = ks * BK;
    #pragma unroll
    for (int it = 0; it < 4; ++it) {
      int r = wid * 32 + it * 8;
      const float4* p = reinterpret_cast<const float4*>(
          A + (size_t)(tm + r + srow) * lda + k0 + scol);
      ar[it][0] = p[0];
      ar[it][1] = p[1];
    }
  };
  auto writeA = [&](int bi) {
    #pragma unroll
    for (int it = 0; it < 4; ++it) {
      int r = wid * 32 + it * 8;
      bf16x8 h;
      h[0] = (short)f2bf(ar[it][0].x); h[1] = (short)f2bf(ar[it][0].y);
      h[2] = (short)f2bf(ar[it][0].z); h[3] = (short)f2bf(ar[it][0].w);
      h[4] = (short)f2bf(ar[it][1].x); h[5] = (short)f2bf(ar[it][1].y);
      h[6] = (short)f2bf(ar[it][1].z); h[7] = (short)f2bf(ar[it][1].w);
      *(bf16x8*)&As[bi][(r + srow) * BK + (lane & 7) * 8] = h;
    }
  };
  auto stageB = [&](int bi, int ks) {
    int k0 = ks * BK;
    #pragma unroll
    for (int it = 0; it < 4; ++it) {
      int r = wid * 32 + it * 8;
      gld16(B + (size_t)(tnBase + r + srow) * ldb + k0 + scol, &Bs[bi][r * BK]);
    }
  };

  loadA(0);
  stageB(0, 0);
  writeA(0);

  for (int ks = 0; ks < nk; ++ks) {
    int bi = ks & 1;
    if (ks + 1 < nk) {
      loadA(ks + 1);
      stageB(bi ^ 1, ks + 1);
      asm volatile("s_waitcnt vmcnt(12)" ::: "memory");
    } else {
      asm volatile("s_waitcnt vmcnt(0)" ::: "memory");
    }
    asm volatile("s_waitcnt lgkmcnt(0)" ::: "memory");
    __builtin_amdgcn_s_barrier();
    __builtin_amdgcn_sched_barrier(0);

    #pragma unroll
    for (int kk = 0; kk < BK; kk += 32) {
      bf16x8 af[4], bfr[4];
      #pragma unroll
      for (int m = 0; m < 4; ++m)
        af[m] = *(const bf16x8*)&As[bi][(wr + m * 16 + lr) * BK + ((kk + kof) ^ rxor)];
      #pragma unroll
      for (int n = 0; n < 4; ++n)
        bfr[n] = *(const bf16x8*)&Bs[bi][(wc + n * 16 + lr) * BK + ((kk + kof) ^ rxor)];
      #pragma unroll
      for (int m = 0; m < 4; ++m)
        #pragma unroll
        for (int n = 0; n < 4; ++n)
          acc[m][n] = __builtin_amdgcn_mfma_f32_16x16x32_bf16(af[m], bfr[n], acc[m][n], 0, 0, 0);
    }
    if (ks + 1 < nk) writeA(bi ^ 1);
    asm volatile("" ::: "memory");
    __builtin_amdgcn_s_barrier();
    __builtin_amdgcn_sched_barrier(0);
  }

  int rb0 = tm + wr + (lane >> 4) * 4;
  #pragma unroll
  for (int m = 0; m < 4; ++m) {
    #pragma unroll
    for (int n = 0; n < 4; ++n) {
      int col = tnBase + wc + n * 16 + lr;
      #pragma unroll
      for (int j = 0; j < 4; ++j) {
        int row = rb0 + m * 16 + j;
        C[(size_t)row * ldc + col] = f2bf(acc[m][n][j]);
      }
    }
  }
}

// ---------------- fallback sentinel ----------------
__global__ void fill_kernel(float* out, int n, float v) {
  int i = blockIdx.x * blockDim.x + threadIdx.x;
  for (; i < n; i += gridDim.x * blockDim.x) out[i] = v;
}

extern "C" void kernel_launch(void* const* d_in, const int* in_sizes, int n_in,
                              void* d_out, int out_size, void* d_ws, size_t ws_size,
                              hipStream_t stream) {
  const float* x  = (const float*)d_in[0];
  const float* W1 = (const float*)d_in[1];
  const float* W2 = (const float*)d_in[2];
  const float* W3 = (const float*)d_in[3];
  float* out = (float*)d_out;

  char* ws = (char*)d_ws;
  size_t off = 0;
  auto alloc = [&](size_t bytes) -> char* {
    char* p = ws + off;
    off += (bytes + 255) & ~(size_t)255;
    return p;
  };

  unsigned short* zb  = (unsigned short*)alloc((size_t)MROWS * PDIM * 2);
  unsigned short* kvb = (unsigned short*)alloc((size_t)MROWS * 2 * PDIM * 2);
  unsigned short* vt  = (unsigned short*)alloc((size_t)BATCH * PDIM * L_SEQ * 2);
  unsigned short* ar  = (unsigned short*)alloc((size_t)MROWS * PDIM * 2);
  unsigned short* w3b = (unsigned short*)alloc((size_t)DOUT * PDIM * 2);
  size_t persist = off;

  char* scratch = ws + persist;
  size_t avail = (ws_size > persist) ? (ws_size - persist) : 0;

  size_t w1B  = ((size_t)PDIM * DIN * 2 + 255) & ~(size_t)255;
  size_t w2B  = ((size_t)2 * PDIM * PDIM * 2 + 255) & ~(size_t)255;
  size_t convNeed = w1B + w2B;

  size_t scores1 = ((size_t)L_SEQ * L_SEQ * 2 + 255) & ~(size_t)255; // 8MB bf16
  size_t per = scores1;

  if (avail < convNeed || avail < per) {
    float sentinel = 1.0e6f + (float)(ws_size >> 20);
    fill_kernel<<<512, 256, 0, stream>>>(out, out_size, sentinel);
    return;
  }

  int c = (int)(avail / per);
  if (c > BATCH) c = BATCH;
  int nch = (BATCH + c - 1) / c;
  c = (BATCH + nch - 1) / nch;

  unsigned short* w1b = (unsigned short*)(scratch);
  unsigned short* w2b = (unsigned short*)(scratch + w1B);
  unsigned short* scores = (unsigned short*)(scratch);  // overlaps w1b/w2b (consumed)

  const float scaling = 0.04419417382415922f;  // 512^-0.5
  const int NTRI = (L_SEQ / BM) * (L_SEQ / BM + 1) / 2;   // 136 lower-tri tiles

  // weights convert (one launch); x is consumed fp32 directly by gemm_a32
  convert3_f32_bf16<<<768, 256, 0, stream>>>(
      W1, w1b, (PDIM * DIN) / 4,
      W2, w2b, (2 * PDIM * PDIM) / 4,
      W3, w3b, (DOUT * PDIM) / 4);

  // GEMM1 (fused cvt, 4-wave — measured best): z = x @ W1^T
  gemm_a32<<<dim3(PDIM / 128, MROWS / BM, 1), 256, 0, stream>>>(
      x, w1b, zb, DIN, DIN, DIN, PDIM);

  // GEMM2: kv = z @ W2^T (8-wave)
  gemm_bt8<0, 0><<<dim3(2 * PDIM / 128, MROWS / BM, 1), 512, 0, stream>>>(
      zb, w2b, kvb, PDIM, PDIM, PDIM, 2 * PDIM, 0, 0, 0);

  // V transpose per batch: vt[b][p][l]
  transpose_v_kernel<<<dim3(L_SEQ / 32, PDIM / 32, BATCH), dim3(32, 8), 0, stream>>>(kvb, vt);

  // ---- chunked attention (c==8 expected: single pass) ----
  for (int b0 = 0; b0 < BATCH; b0 += c) {
    int cb = (BATCH - b0 < c) ? (BATCH - b0) : c;

    // scores[z] = Q @ K^T (bf16), triangular tiles (8-wave)
    gemm_bt8<0, 1><<<dim3(NTRI, 1, cb), 512, 0, stream>>>(
        zb + (size_t)b0 * PDIM, kvb + (size_t)b0 * 2 * PDIM, scores,
        PDIM, BATCH * PDIM, BATCH * 2 * PDIM, L_SEQ,
        (size_t)PDIM, (size_t)2 * PDIM, (size_t)L_SEQ * L_SEQ);

    softmax_causal<<<dim3(L_SEQ, 1, cb), 256, 0, stream>>>(
        scores, (size_t)L_SEQ * L_SEQ, scaling);

    // attn_out + residual -> ar (bf16): 8-wave PV, causal, rows descending
    gemm_pv8<<<dim3(PDIM / 64, L_SEQ / BM, cb), 512, 0, stream>>>(
        scores, vt + (size_t)b0 * PDIM * L_SEQ, ar + (size_t)b0 * PDIM,
        zb + (size_t)b0 * PDIM,
        L_SEQ, L_SEQ, L_SEQ, L_SEQ, BATCH * PDIM,
        (size_t)L_SEQ * L_SEQ, (size_t)PDIM * L_SEQ, (size_t)PDIM, (size_t)PDIM);
  }

  // GEMM3: out = (attn + residual) @ W3^T -> fp32 (8-wave)
  gemm_bt8<1, 0><<<dim3(DOUT / 128, MROWS / BM, 1), 512, 0, stream>>>(
      ar, w3b, out, PDIM, PDIM, PDIM, DOUT, 0, 0, 0);
}